// Round 9
// baseline (2077.276 us; speedup 1.0000x reference)
//
#include <hip/hip_runtime.h>
#include <float.h>
#include <math.h>
#include <stdint.h>

// Problem constants (match reference)
constexpr int B   = 8;
constexpr int C   = 96;
constexpr int N   = 3136;   // 56*56
constexpr int M   = 784;    // RATIO*N
constexpr int C4  = 384;    // 4*C
constexpr int OUT = 192;
constexpr int KD  = 16;     // K_DPC
constexpr int TK  = 5;      // TOPK

// ---------------------------------------------------------------------------
// fp32 round-to-nearest of a positive double WITH flush-to-zero of subnormal
// results (validated semantics for the reference's exp underflow).
__device__ inline uint32_t f32q_ftz(double t) {
    if (t <= 0.0) return 0u;
    float f = (float)t;              // exact RN cvt (double->float)
    if (f < 0x1p-126f) return 0u;    // subnormal result -> flush to zero
    return __float_as_uint(f);
}

// ---------------------------------------------------------------------------
// K0: per-point squared norms of y and x (both laid out (B,C,N))
__global__ __launch_bounds__(256) void k_norms(const float* __restrict__ y,
                                               const float* __restrict__ x,
                                               float* __restrict__ ynorm,
                                               float* __restrict__ xnorm) {
    int id = blockIdx.x * 256 + threadIdx.x;
    if (id >= B * N) return;
    int b = id / N, n = id % N;
    const float* yb = y + (size_t)b * C * N + n;
    const float* xb = x + (size_t)b * C * N + n;
    float sy = 0.f, sx = 0.f;
    #pragma unroll 8
    for (int c = 0; c < C; ++c) {
        float a = yb[(size_t)c * N]; sy += a * a;
        float d = xb[(size_t)c * N]; sx += d * d;
    }
    ynorm[id] = sy;
    xnorm[id] = sx;
}

// ---------------------------------------------------------------------------
// K1 v5: 16 rows/block, 256 threads, 4 cols/thread, 4 tiles of 1024 cols.
// dv computed IN PLACE on acc (keeps VGPR ~110, no spill). LDS rows padded
// (257 / 17 / 129) so owner-phase scans are bank-conflict-free.
// d expression / c-order / mean tree / FTZ exp / value-multiset selection
// identical to the validated round-7/8 kernel.
constexpr int DR = 16;      // rows per block
constexpr int DCOLS = 1024; // cols per tile

__global__ __launch_bounds__(256) void k_density(const float* __restrict__ y,
                                                 const float* __restrict__ rel,
                                                 const float* __restrict__ ynorm,
                                                 uint32_t* __restrict__ densbits,
                                                 float* __restrict__ rowmax) {
    const int b  = blockIdx.y;
    const int i0 = blockIdx.x * DR;
    const int t  = threadIdx.x;

    __shared__ __align__(16) float yiS[DR][100];
    __shared__ float niS[DR];
    __shared__ float s16[DR][17];     // per-row sorted top-16 (ascending), padded
    __shared__ float thrS[DR];
    __shared__ float minb[DR][257];   // per-thread minima / rowmax scratch, padded
    __shared__ float candV[DR][129];  // per-tile candidates, padded
    __shared__ int   candC[DR];

    const float* yb = y + (size_t)b * C * N;

    // stage A-panel: yiS[r][c] = y[c][i0+r]  (DR/4 = 4 groups of 4 rows)
    for (int e = t; e < C * (DR / 4); e += 256) {
        int c = e >> 2, n4 = (e & 3) << 2;
        float4 v = *reinterpret_cast<const float4*>(yb + (size_t)c * N + i0 + n4);
        yiS[n4 + 0][c] = v.x;
        yiS[n4 + 1][c] = v.y;
        yiS[n4 + 2][c] = v.z;
        yiS[n4 + 3][c] = v.w;
    }
    if (t < DR) {
        niS[t] = ynorm[b * N + i0 + t];
        thrS[t] = FLT_MAX;
        candC[t] = 0;
        #pragma unroll
        for (int q = 0; q < 16; ++q) s16[t][q] = FLT_MAX;
    }
    float rm[DR];
    #pragma unroll
    for (int r = 0; r < DR; ++r) rm[r] = -FLT_MAX;
    __syncthreads();

    for (int tile = 0; tile < 4; ++tile) {
        const int jt = tile * DCOLS + 4 * t;
        const bool active = (jt < N);

        float acc[DR][4];
        #pragma unroll
        for (int r = 0; r < DR; ++r)
            #pragma unroll
            for (int q = 0; q < 4; ++q) acc[r][q] = 0.f;

        if (active) {
            for (int c0 = 0; c0 < C; c0 += 4) {
                float4 bq0 = *reinterpret_cast<const float4*>(yb + (size_t)(c0 + 0) * N + jt);
                float4 bq1 = *reinterpret_cast<const float4*>(yb + (size_t)(c0 + 1) * N + jt);
                float4 bq2 = *reinterpret_cast<const float4*>(yb + (size_t)(c0 + 2) * N + jt);
                float4 bq3 = *reinterpret_cast<const float4*>(yb + (size_t)(c0 + 3) * N + jt);
                #pragma unroll
                for (int r = 0; r < DR; ++r) {
                    float4 a4 = *reinterpret_cast<const float4*>(&yiS[r][c0]);
                    // sequential c accumulation order (c0, c0+1, c0+2, c0+3)
                    acc[r][0] += a4.x * bq0.x; acc[r][1] += a4.x * bq0.y;
                    acc[r][2] += a4.x * bq0.z; acc[r][3] += a4.x * bq0.w;
                    acc[r][0] += a4.y * bq1.x; acc[r][1] += a4.y * bq1.y;
                    acc[r][2] += a4.y * bq1.z; acc[r][3] += a4.y * bq1.w;
                    acc[r][0] += a4.z * bq2.x; acc[r][1] += a4.z * bq2.y;
                    acc[r][2] += a4.z * bq2.z; acc[r][3] += a4.z * bq2.w;
                    acc[r][0] += a4.w * bq3.x; acc[r][1] += a4.w * bq3.y;
                    acc[r][2] += a4.w * bq3.z; acc[r][3] += a4.w * bq3.w;
                }
            }

            // epilogue: d in place of acc; per-thread row maxima
            float4 yn4 = *reinterpret_cast<const float4*>(ynorm + (size_t)b * N + jt);
            float yn[4] = {yn4.x, yn4.y, yn4.z, yn4.w};
            #pragma unroll
            for (int r = 0; r < DR; ++r) {
                float4 rl4 = *reinterpret_cast<const float4*>(rel + (size_t)(i0 + r) * N + jt);
                float rl[4] = {rl4.x, rl4.y, rl4.z, rl4.w};
                float niv = niS[r];
                #pragma unroll
                for (int q = 0; q < 4; ++q)
                    acc[r][q] = niv + yn[q] - 2.f * acc[r][q] + rl[q];
                rm[r] = fmaxf(rm[r],
                        fmaxf(fmaxf(acc[r][0], acc[r][1]), fmaxf(acc[r][2], acc[r][3])));
            }
        }

        if (tile == 0) {
            // seed exact-safe threshold: T0 = 16th smallest of 256 thread minima
            #pragma unroll
            for (int r = 0; r < DR; ++r) {
                float mn = active
                    ? fminf(fminf(acc[r][0], acc[r][1]), fminf(acc[r][2], acc[r][3]))
                    : FLT_MAX;
                minb[r][t] = mn;
            }
            __syncthreads();
            if (t < DR) {
                #pragma unroll
                for (int q = 0; q < 16; ++q) candV[t][q] = FLT_MAX;
                for (int e = 0; e < 256; ++e) {
                    float v = minb[t][e];
                    if (v < candV[t][15]) {
                        int pos = 15;
                        while (pos > 0 && candV[t][pos - 1] > v) {
                            candV[t][pos] = candV[t][pos - 1];
                            --pos;
                        }
                        candV[t][pos] = v;
                    }
                }
                thrS[t] = candV[t][15];
            }
            __syncthreads();
        }

        // candidate filter (tile0 uses <= T0 — provably <= 64 candidates;
        // later tiles < running 16th)
        if (active) {
            #pragma unroll
            for (int r = 0; r < DR; ++r) {
                float thr = thrS[r];
                #pragma unroll
                for (int q = 0; q < 4; ++q) {
                    float v = acc[r][q];
                    bool take = (tile == 0) ? (v <= thr) : (v < thr);
                    if (take) {
                        int p = atomicAdd(&candC[r], 1);
                        if (p < 128) candV[r][p] = v;
                    }
                }
            }
        }
        __syncthreads();

        // owner threads insert candidates (order-independent, exact)
        if (t < DR) {
            int cnt = candC[t];
            if (cnt > 128) cnt = 128;
            for (int qq = 0; qq < cnt; ++qq) {
                float v = candV[t][qq];
                if (v < s16[t][15]) {
                    int pos = 15;
                    while (pos > 0 && s16[t][pos - 1] > v) {
                        s16[t][pos] = s16[t][pos - 1];
                        --pos;
                    }
                    s16[t][pos] = v;
                }
            }
            candC[t] = 0;
            thrS[t] = s16[t][15];
        }
        __syncthreads();
    }

    // rowmax reduce + density
    #pragma unroll
    for (int r = 0; r < DR; ++r) minb[r][t] = rm[r];
    __syncthreads();
    if (t < DR) {
        float mx = -FLT_MAX;
        for (int e = 0; e < 256; ++e) mx = fmaxf(mx, minb[t][e]);
        rowmax[b * N + i0 + t] = mx;

        // numpy pairwise fp32 sum of the 16 ascending values
        float r8[8];
        #pragma unroll
        for (int j2 = 0; j2 < 8; ++j2) r8[j2] = s16[t][j2] + s16[t][8 + j2];
        float s = ((r8[0] + r8[1]) + (r8[2] + r8[3]))
                + ((r8[4] + r8[5]) + (r8[6] + r8[7]));
        float mean = s * (1.0f / 16.0f);
        densbits[b * N + i0 + t] = f32q_ftz(exp(-(double)mean));
    }
}

// ---------------------------------------------------------------------------
// K2: per-batch global max of d (fp32)
__global__ __launch_bounds__(256) void k_dmax(const float* __restrict__ rowmax,
                                              float* __restrict__ dmax) {
    int b = blockIdx.x, t = threadIdx.x;
    __shared__ float rv[256];
    float lm = -FLT_MAX;
    for (int j = t; j < N; j += 256) lm = fmaxf(lm, rowmax[b * N + j]);
    rv[t] = lm;
    __syncthreads();
    for (int s = 128; s > 0; s >>= 1) {
        if (t < s) rv[t] = fmaxf(rv[t], rv[t + s]);
        __syncthreads();
    }
    if (t == 0) dmax[b] = rv[0];
}

// ---------------------------------------------------------------------------
// K3: dist_peak = min over j with dens[j] > dens[i] of d[i,j] (else dmax);
// score = fp32(dist_peak * density) emulated exactly; packed rank key.
__global__ __launch_bounds__(256) void k_score(const float* __restrict__ y,
                                               const float* __restrict__ rel,
                                               const float* __restrict__ ynorm,
                                               const uint32_t* __restrict__ densbits,
                                               const float* __restrict__ dmax,
                                               unsigned long long* __restrict__ keys) {
    const int i = blockIdx.x;
    const int b = blockIdx.y;
    const int t = threadIdx.x;

    const uint32_t bi = densbits[b * N + i];
    if (bi == 0u) {   // score == +0.0 exactly; key = (0, ~idx)
        if (t == 0) keys[b * N + i] =
            (unsigned long long)(0xFFFFFFFFu - (uint32_t)i);
        return;
    }

    __shared__ float yi[C];
    __shared__ float rv[256];

    const float* yb = y + (size_t)b * C * N;
    if (t < C) yi[t] = yb[(size_t)t * N + i];
    __syncthreads();

    const float ni = ynorm[b * N + i];
    float mn = FLT_MAX;
    for (int j = t; j < N; j += 256) {
        if (densbits[b * N + j] > bi) {
            const float* p = yb + j;
            float dot = 0.f;
            #pragma unroll 8
            for (int c = 0; c < C; ++c) dot += yi[c] * p[(size_t)c * N];
            float d = ni + ynorm[b * N + j] - 2.f * dot + rel[(size_t)i * N + j];
            mn = fminf(mn, d);
        }
    }
    rv[t] = mn;
    __syncthreads();
    for (int s = 128; s > 0; s >>= 1) {
        if (t < s) rv[t] = fminf(rv[t], rv[t + s]);
        __syncthreads();
    }
    if (t == 0) {
        float dp = fminf(rv[0], dmax[b]);
        double p = (double)dp * (double)__uint_as_float(bi);
        float sf = (float)p;
        uint32_t sb = (sf < 0x1p-126f) ? 0u : __float_as_uint(sf);
        keys[b * N + i] = ((unsigned long long)sb << 32)
                        | (unsigned long long)(0xFFFFFFFFu - (uint32_t)i);
    }
}

// ---------------------------------------------------------------------------
// K4: per-batch bitonic sort of packed keys, descending -> top M indices.
__global__ __launch_bounds__(512) void k_topm(const unsigned long long* __restrict__ keys,
                                              int* __restrict__ sidx) {
    constexpr int SZ = 4096;
    int b = blockIdx.x, t = threadIdx.x;
    __shared__ unsigned long long ks[SZ];
    for (int i = t; i < SZ; i += 512) ks[i] = (i < N) ? keys[b * N + i] : 0ull;
    __syncthreads();
    for (int k = 2; k <= SZ; k <<= 1) {
        for (int j = k >> 1; j > 0; j >>= 1) {
            for (int i = t; i < SZ; i += 512) {
                int ixj = i ^ j;
                if (ixj > i) {
                    bool up = ((i & k) == 0);
                    unsigned long long a = ks[i], c2 = ks[ixj];
                    bool doSwap = up ? (a < c2) : (a > c2);  // descending
                    if (doSwap) { ks[i] = c2; ks[ixj] = a; }
                }
            }
            __syncthreads();
        }
    }
    for (int m = t; m < M; m += 512)
        sidx[b * M + m] = (int)(0xFFFFFFFFu - (uint32_t)(ks[m] & 0xFFFFFFFFull));
}

// ---------------------------------------------------------------------------
// K5 v2: gather centers TRANSPOSED: cenT[b][c][m] = y[b][c][sidx[m]].
__global__ __launch_bounds__(256) void k_cen(const float* __restrict__ y,
                                             const int* __restrict__ sidx,
                                             const float* __restrict__ ynorm,
                                             float* __restrict__ cenT,
                                             float* __restrict__ cnorm) {
    const int b = blockIdx.y;
    const int m = blockIdx.x * 256 + threadIdx.x;
    if (m >= M) return;
    const int j = sidx[b * M + m];
    cnorm[b * M + m] = ynorm[b * N + j];
    const float* yb = y + (size_t)b * C * N;
    float* ct = cenT + (size_t)b * C * M;
    #pragma unroll 8
    for (int c = 0; c < C; ++c)
        ct[(size_t)c * M + m] = yb[(size_t)c * N + j];
}

// ---------------------------------------------------------------------------
// K6 v2 (validated round 8): tiled assignment GEMM + softmax + top-5.
__global__ __launch_bounds__(256) void k_assign(const float* __restrict__ x,
                                                const float* __restrict__ cenT,
                                                const float* __restrict__ xnorm,
                                                const float* __restrict__ cnorm,
                                                float* __restrict__ assign,
                                                int* __restrict__ nnidx) {
    const int b  = blockIdx.y;
    const int i0 = blockIdx.x * 8;
    const int t  = threadIdx.x;

    __shared__ __align__(16) float xiS[8][100];
    __shared__ __align__(16) float Ss[8][788];
    __shared__ float xnS[8];

    const float* xb = x + (size_t)b * C * N;
    const float* ct = cenT + (size_t)b * C * M;

    for (int e = t; e < C * 2; e += 256) {
        int c = e >> 1, n4 = (e & 1) << 2;
        float4 v = *reinterpret_cast<const float4*>(xb + (size_t)c * N + i0 + n4);
        xiS[n4 + 0][c] = v.x;
        xiS[n4 + 1][c] = v.y;
        xiS[n4 + 2][c] = v.z;
        xiS[n4 + 3][c] = v.w;
    }
    if (t < 8) xnS[t] = xnorm[b * N + i0 + t];
    __syncthreads();

    if (t < 196) {
        const int mt = 4 * t;
        float acc[8][4];
        #pragma unroll
        for (int r = 0; r < 8; ++r)
            #pragma unroll
            for (int q = 0; q < 4; ++q) acc[r][q] = 0.f;

        for (int c0 = 0; c0 < C; c0 += 4) {
            float4 bq0 = *reinterpret_cast<const float4*>(ct + (size_t)(c0 + 0) * M + mt);
            float4 bq1 = *reinterpret_cast<const float4*>(ct + (size_t)(c0 + 1) * M + mt);
            float4 bq2 = *reinterpret_cast<const float4*>(ct + (size_t)(c0 + 2) * M + mt);
            float4 bq3 = *reinterpret_cast<const float4*>(ct + (size_t)(c0 + 3) * M + mt);
            #pragma unroll
            for (int r = 0; r < 8; ++r) {
                float4 a4 = *reinterpret_cast<const float4*>(&xiS[r][c0]);
                acc[r][0] += a4.x * bq0.x; acc[r][1] += a4.x * bq0.y;
                acc[r][2] += a4.x * bq0.z; acc[r][3] += a4.x * bq0.w;
                acc[r][0] += a4.y * bq1.x; acc[r][1] += a4.y * bq1.y;
                acc[r][2] += a4.y * bq1.z; acc[r][3] += a4.y * bq1.w;
                acc[r][0] += a4.z * bq2.x; acc[r][1] += a4.z * bq2.y;
                acc[r][2] += a4.z * bq2.z; acc[r][3] += a4.z * bq2.w;
                acc[r][0] += a4.w * bq3.x; acc[r][1] += a4.w * bq3.y;
                acc[r][2] += a4.w * bq3.z; acc[r][3] += a4.w * bq3.w;
            }
        }

        float4 cn4 = *reinterpret_cast<const float4*>(cnorm + (size_t)b * M + mt);
        float cn[4] = {cn4.x, cn4.y, cn4.z, cn4.w};
        #pragma unroll
        for (int r = 0; r < 8; ++r) {
            float xn = xnS[r];
            float sv[4];
            #pragma unroll
            for (int q = 0; q < 4; ++q)
                sv[q] = -(xn + cn[q] - 2.f * acc[r][q]);
            *reinterpret_cast<float4*>(&Ss[r][mt]) =
                make_float4(sv[0], sv[1], sv[2], sv[3]);
        }
    }
    __syncthreads();

    const int r = t >> 5;
    const int l = t & 31;

    float lm = -FLT_MAX;
    for (int m = l; m < M; m += 32) lm = fmaxf(lm, Ss[r][m]);
    #pragma unroll
    for (int off = 16; off > 0; off >>= 1)
        lm = fmaxf(lm, __shfl_xor(lm, off, 32));
    const float smax = lm;

    float ls = 0.f;
    for (int m = l; m < M; m += 32) ls += expf(Ss[r][m] - smax);
    #pragma unroll
    for (int off = 16; off > 0; off >>= 1)
        ls += __shfl_xor(ls, off, 32);
    const float inv = 1.f / ls;

    float* arow = assign + ((size_t)b * N + i0 + r) * M;
    for (int m = l; m < M; m += 32) arow[m] = expf(Ss[r][m] - smax) * inv;

    for (int round = 0; round < TK; ++round) {
        float lv = -FLT_MAX; int li = M;
        for (int m = l; m < M; m += 32) {
            float v = Ss[r][m];
            if (v > lv) { lv = v; li = m; }
        }
        #pragma unroll
        for (int off = 16; off > 0; off >>= 1) {
            float ov = __shfl_xor(lv, off, 32);
            int   oi = __shfl_xor(li, off, 32);
            if (ov > lv || (ov == lv && oi < li)) { lv = ov; li = oi; }
        }
        if (l == 0) {
            nnidx[((size_t)b * N + i0 + r) * TK + round] = li;
            Ss[r][li] = -FLT_MAX;
        }
        __syncthreads();
    }
}

// ---------------------------------------------------------------------------
// K7: agg[b,m,c] = (sum_n assign[n,m] * x[c,n]) / (mass_m + 1e-6)
__global__ __launch_bounds__(256) void k_agg(const float* __restrict__ assign,
                                             const float* __restrict__ x,
                                             float* __restrict__ aggws) {
    const int b = blockIdx.y;
    const int m0 = blockIdx.x * 16;
    const int t = threadIdx.x;
    __shared__ float As[64][16];
    __shared__ float Xs[96][65];
    __shared__ float minv[16];

    float acc[6] = {0.f, 0.f, 0.f, 0.f, 0.f, 0.f};
    float massacc = 0.f;

    for (int n0 = 0; n0 < N; n0 += 64) {
        for (int e = t; e < 64 * 16; e += 256) {
            int nn = e >> 4, mm = e & 15;
            As[nn][mm] = assign[((size_t)b * N + n0 + nn) * M + m0 + mm];
        }
        for (int e = t; e < 96 * 64; e += 256) {
            int c = e >> 6, nn = e & 63;
            Xs[c][nn] = x[((size_t)b * C + c) * N + n0 + nn];
        }
        __syncthreads();
        if (t < 16) {
            #pragma unroll
            for (int nn = 0; nn < 64; ++nn) massacc += As[nn][t];
        }
        #pragma unroll
        for (int u = 0; u < 6; ++u) {
            int e = t + u * 256;
            int mm = e & 15, c = e >> 4;
            float a = acc[u];
            #pragma unroll 8
            for (int nn = 0; nn < 64; ++nn) a += As[nn][mm] * Xs[c][nn];
            acc[u] = a;
        }
        __syncthreads();
    }
    if (t < 16) minv[t] = 1.f / (massacc + 1e-6f);
    __syncthreads();
    #pragma unroll
    for (int u = 0; u < 6; ++u) {
        int e = t + u * 256;
        int mm = e & 15, c = e >> 4;
        aggws[((size_t)b * M + m0 + mm) * C + c] = acc[u] * minv[mm];
    }
}

// ---------------------------------------------------------------------------
// K8: per-center FFN with residual; writes updated agg (ws) and `refined`
__global__ __launch_bounds__(128) void k_ffn(const float* __restrict__ w1,
                                             const float* __restrict__ b1,
                                             const float* __restrict__ g1,
                                             const float* __restrict__ bt1,
                                             const float* __restrict__ w2,
                                             const float* __restrict__ b2,
                                             const float* __restrict__ g2,
                                             const float* __restrict__ bt2,
                                             float* __restrict__ aggws,
                                             float* __restrict__ refined) {
    const int m = blockIdx.x;
    const int b = blockIdx.y;
    const int t = threadIdx.x;
    __shared__ float ar[C];
    __shared__ float hd[C4];

    if (t < C) ar[t] = aggws[((size_t)b * M + m) * C + t];
    __syncthreads();

    for (int o = t; o < C4; o += 128) {
        const float* w = w1 + (size_t)o * C;
        float h = b1[o];
        #pragma unroll 8
        for (int c = 0; c < C; ++c) h += w[c] * ar[c];
        h = h * g1[o] + bt1[o];
        hd[o] = fmaxf(h, 0.f);
    }
    __syncthreads();

    if (t < C) {
        const float* w = w2 + (size_t)t * C4;
        float f = b2[t];
        #pragma unroll 8
        for (int o = 0; o < C4; ++o) f += w[o] * hd[o];
        float v = ar[t] + (f * g2[t] + bt2[t]);
        aggws[((size_t)b * M + m) * C + t] = v;
        refined[((size_t)b * C + t) * M + m] = v;
    }
}

// ---------------------------------------------------------------------------
// K9: rel = max over top-5 agg rows - xf; interleaved xcat;
// out = relu((nn_w @ xcat + nn_b) * g + bt), stored (B, OUT, N)
__global__ __launch_bounds__(256) void k_final(const float* __restrict__ x,
                                               const float* __restrict__ aggws,
                                               const int* __restrict__ nnidx,
                                               const float* __restrict__ nnw,
                                               const float* __restrict__ nnb,
                                               const float* __restrict__ nng,
                                               const float* __restrict__ nnbt,
                                               float* __restrict__ out) {
    const int b = blockIdx.y;
    const int n0 = blockIdx.x * 16;
    const int t = threadIdx.x;
    __shared__ float xc[16][193];
    __shared__ int nid[16 * TK];

    if (t < 16 * TK) nid[t] = nnidx[((size_t)b * N + n0) * TK + t];
    __syncthreads();

    for (int e = t; e < C * 16; e += 256) {
        int c = e >> 4, r = e & 15;
        float xv = x[((size_t)b * C + c) * N + n0 + r];
        float mx = -FLT_MAX;
        #pragma unroll
        for (int k = 0; k < TK; ++k) {
            int j = nid[r * TK + k];
            mx = fmaxf(mx, aggws[((size_t)b * M + j) * C + c]);
        }
        xc[r][2 * c]     = xv;
        xc[r][2 * c + 1] = mx - xv;
    }
    __syncthreads();

    const int r = t & 15;
    const int og = t >> 4;
    #pragma unroll
    for (int oo = 0; oo < 12; ++oo) {
        int o = og + (oo << 4);
        const float* w = nnw + (size_t)o * (2 * C);
        float a = nnb[o];
        #pragma unroll 8
        for (int cc = 0; cc < 2 * C; ++cc) a += w[cc] * xc[r][cc];
        a = a * nng[o] + nnbt[o];
        out[((size_t)b * OUT + o) * N + n0 + r] = fmaxf(a, 0.f);
    }
}

// ---------------------------------------------------------------------------
extern "C" void kernel_launch(void* const* d_in, const int* in_sizes, int n_in,
                              void* d_out, int out_size, void* d_ws, size_t ws_size,
                              hipStream_t stream) {
    const float* x    = (const float*)d_in[0];
    const float* rel  = (const float*)d_in[1];
    const float* y    = (const float*)d_in[2];
    const float* w1   = (const float*)d_in[3];
    const float* b1   = (const float*)d_in[4];
    const float* g1   = (const float*)d_in[5];
    const float* bt1  = (const float*)d_in[6];
    const float* w2   = (const float*)d_in[7];
    const float* b2   = (const float*)d_in[8];
    const float* g2   = (const float*)d_in[9];
    const float* bt2  = (const float*)d_in[10];
    const float* nnw  = (const float*)d_in[11];
    const float* nnb  = (const float*)d_in[12];
    const float* nng  = (const float*)d_in[13];
    const float* nnbt = (const float*)d_in[14];

    float* out     = (float*)d_out;
    float* refined = out + (size_t)B * OUT * N;

    char* w = (char*)d_ws;
    auto alloc = [&](size_t nbytes) -> void* {
        void* p = (void*)w;
        w += (nbytes + 255) & ~(size_t)255;
        return p;
    };
    float*    ynorm    = (float*)   alloc((size_t)B * N * 4);
    float*    xnorm    = (float*)   alloc((size_t)B * N * 4);
    uint32_t* densbits = (uint32_t*)alloc((size_t)B * N * 4);
    float*    rowmax   = (float*)   alloc((size_t)B * N * 4);
    float*    dmaxv    = (float*)   alloc((size_t)B * 4);
    unsigned long long* keys = (unsigned long long*)alloc((size_t)B * N * 8);
    int*      sidx     = (int*)     alloc((size_t)B * M * 4);
    float*    cnorm    = (float*)   alloc((size_t)B * M * 4);
    float*    cenT     = (float*)   alloc((size_t)B * C * M * 4);
    float*    aggws    = (float*)   alloc((size_t)B * M * C * 4);
    int*      nnidx    = (int*)     alloc((size_t)B * N * TK * 4);
    float*    assign   = (float*)   alloc((size_t)B * N * M * 4);

    k_norms<<<dim3((B * N + 255) / 256), dim3(256), 0, stream>>>(y, x, ynorm, xnorm);
    k_density<<<dim3(N / DR, B), dim3(256), 0, stream>>>(y, rel, ynorm, densbits, rowmax);
    k_dmax<<<dim3(B), dim3(256), 0, stream>>>(rowmax, dmaxv);
    k_score<<<dim3(N, B), dim3(256), 0, stream>>>(y, rel, ynorm, densbits, dmaxv, keys);
    k_topm<<<dim3(B), dim3(512), 0, stream>>>(keys, sidx);
    k_cen<<<dim3((M + 255) / 256, B), dim3(256), 0, stream>>>(y, sidx, ynorm, cenT, cnorm);
    k_assign<<<dim3(N / 8, B), dim3(256), 0, stream>>>(x, cenT, xnorm, cnorm, assign, nnidx);
    k_agg<<<dim3(M / 16, B), dim3(256), 0, stream>>>(assign, x, aggws);
    k_ffn<<<dim3(M, B), dim3(128), 0, stream>>>(w1, b1, g1, bt1, w2, b2, g2, bt2, aggws, refined);
    k_final<<<dim3(N / 16, B), dim3(256), 0, stream>>>(x, aggws, nnidx, nnw, nnb, nng, nnbt, out);
}

// Round 10
// 1801.333 us; speedup vs baseline: 1.1532x; 1.1532x over previous
//
#include <hip/hip_runtime.h>
#include <float.h>
#include <math.h>
#include <stdint.h>

// Problem constants (match reference)
constexpr int B   = 8;
constexpr int C   = 96;
constexpr int N   = 3136;   // 56*56
constexpr int M   = 784;    // RATIO*N
constexpr int C4  = 384;    // 4*C
constexpr int OUT = 192;
constexpr int KD  = 16;     // K_DPC
constexpr int TK  = 5;      // TOPK

// ---------------------------------------------------------------------------
// fp32 round-to-nearest of a positive double WITH flush-to-zero of subnormal
// results (validated semantics for the reference's exp underflow).
__device__ inline uint32_t f32q_ftz(double t) {
    if (t <= 0.0) return 0u;
    float f = (float)t;              // exact RN cvt (double->float)
    if (f < 0x1p-126f) return 0u;    // subnormal result -> flush to zero
    return __float_as_uint(f);
}

// ---------------------------------------------------------------------------
// K0: per-point squared norms of y and x (both laid out (B,C,N))
__global__ __launch_bounds__(256) void k_norms(const float* __restrict__ y,
                                               const float* __restrict__ x,
                                               float* __restrict__ ynorm,
                                               float* __restrict__ xnorm) {
    int id = blockIdx.x * 256 + threadIdx.x;
    if (id >= B * N) return;
    int b = id / N, n = id % N;
    const float* yb = y + (size_t)b * C * N + n;
    const float* xb = x + (size_t)b * C * N + n;
    float sy = 0.f, sx = 0.f;
    #pragma unroll 8
    for (int c = 0; c < C; ++c) {
        float a = yb[(size_t)c * N]; sy += a * a;
        float d = xb[(size_t)c * N]; sx += d * d;
    }
    ynorm[id] = sy;
    xnorm[id] = sx;
}

// ---------------------------------------------------------------------------
// K1 v6: the validated DR=8 round-8 kernel (775 us, VGPR 60, occ 37%) with
// ONLY the bank-conflict padding applied: minb[.][257], candV[.][193],
// s16[.][17] so the 8 owner threads hit distinct banks in their scans.
// All arithmetic / selection logic identical to the validated version.
constexpr int DR = 8;       // rows per block
constexpr int DCOLS = 1024; // cols per tile

__global__ __launch_bounds__(256) void k_density(const float* __restrict__ y,
                                                 const float* __restrict__ rel,
                                                 const float* __restrict__ ynorm,
                                                 uint32_t* __restrict__ densbits,
                                                 float* __restrict__ rowmax) {
    const int b  = blockIdx.y;
    const int i0 = blockIdx.x * DR;
    const int t  = threadIdx.x;

    __shared__ __align__(16) float yiS[DR][100];
    __shared__ float niS[DR];
    __shared__ float s16[DR][17];     // sorted top-16 asc, padded row
    __shared__ float thrS[DR];
    __shared__ float minb[DR][257];   // per-thread minima / rowmax, padded row
    __shared__ float candV[DR][193];  // candidates, padded row
    __shared__ int   candC[DR];

    const float* yb = y + (size_t)b * C * N;

    // stage A-panel: yiS[r][c] = y[c][i0+r]
    for (int e = t; e < C * 2; e += 256) {
        int c = e >> 1, n4 = (e & 1) << 2;
        float4 v = *reinterpret_cast<const float4*>(yb + (size_t)c * N + i0 + n4);
        yiS[n4 + 0][c] = v.x;
        yiS[n4 + 1][c] = v.y;
        yiS[n4 + 2][c] = v.z;
        yiS[n4 + 3][c] = v.w;
    }
    if (t < DR) {
        niS[t] = ynorm[b * N + i0 + t];
        thrS[t] = FLT_MAX;
        candC[t] = 0;
        #pragma unroll
        for (int q = 0; q < 16; ++q) s16[t][q] = FLT_MAX;
    }
    float rm[DR];
    #pragma unroll
    for (int r = 0; r < DR; ++r) rm[r] = -FLT_MAX;
    __syncthreads();

    for (int tile = 0; tile < 4; ++tile) {
        const int jt = tile * DCOLS + 4 * t;
        const bool active = (jt < N);

        float acc[DR][4];
        #pragma unroll
        for (int r = 0; r < DR; ++r)
            #pragma unroll
            for (int q = 0; q < 4; ++q) acc[r][q] = 0.f;

        float dv[DR][4];

        if (active) {
            for (int c0 = 0; c0 < C; c0 += 4) {
                float4 bq0 = *reinterpret_cast<const float4*>(yb + (size_t)(c0 + 0) * N + jt);
                float4 bq1 = *reinterpret_cast<const float4*>(yb + (size_t)(c0 + 1) * N + jt);
                float4 bq2 = *reinterpret_cast<const float4*>(yb + (size_t)(c0 + 2) * N + jt);
                float4 bq3 = *reinterpret_cast<const float4*>(yb + (size_t)(c0 + 3) * N + jt);
                #pragma unroll
                for (int r = 0; r < DR; ++r) {
                    float4 a4 = *reinterpret_cast<const float4*>(&yiS[r][c0]);
                    // sequential c accumulation order (c0, c0+1, c0+2, c0+3)
                    acc[r][0] += a4.x * bq0.x; acc[r][1] += a4.x * bq0.y;
                    acc[r][2] += a4.x * bq0.z; acc[r][3] += a4.x * bq0.w;
                    acc[r][0] += a4.y * bq1.x; acc[r][1] += a4.y * bq1.y;
                    acc[r][2] += a4.y * bq1.z; acc[r][3] += a4.y * bq1.w;
                    acc[r][0] += a4.z * bq2.x; acc[r][1] += a4.z * bq2.y;
                    acc[r][2] += a4.z * bq2.z; acc[r][3] += a4.z * bq2.w;
                    acc[r][0] += a4.w * bq3.x; acc[r][1] += a4.w * bq3.y;
                    acc[r][2] += a4.w * bq3.z; acc[r][3] += a4.w * bq3.w;
                }
            }

            float4 yn4 = *reinterpret_cast<const float4*>(ynorm + (size_t)b * N + jt);
            float yn[4] = {yn4.x, yn4.y, yn4.z, yn4.w};
            #pragma unroll
            for (int r = 0; r < DR; ++r) {
                float4 rl4 = *reinterpret_cast<const float4*>(rel + (size_t)(i0 + r) * N + jt);
                float rl[4] = {rl4.x, rl4.y, rl4.z, rl4.w};
                float niv = niS[r];
                #pragma unroll
                for (int q = 0; q < 4; ++q)
                    dv[r][q] = niv + yn[q] - 2.f * acc[r][q] + rl[q];
                rm[r] = fmaxf(rm[r],
                        fmaxf(fmaxf(dv[r][0], dv[r][1]), fmaxf(dv[r][2], dv[r][3])));
            }
        }

        if (tile == 0) {
            // seed exact-safe threshold: T0 = 16th smallest of 256 thread minima
            #pragma unroll
            for (int r = 0; r < DR; ++r) {
                float mn = active
                    ? fminf(fminf(dv[r][0], dv[r][1]), fminf(dv[r][2], dv[r][3]))
                    : FLT_MAX;
                minb[r][t] = mn;
            }
            __syncthreads();
            if (t < DR) {
                #pragma unroll
                for (int q = 0; q < 16; ++q) candV[t][q] = FLT_MAX;
                for (int e = 0; e < 256; ++e) {
                    float v = minb[t][e];
                    if (v < candV[t][15]) {
                        int pos = 15;
                        while (pos > 0 && candV[t][pos - 1] > v) {
                            candV[t][pos] = candV[t][pos - 1];
                            --pos;
                        }
                        candV[t][pos] = v;
                    }
                }
                thrS[t] = candV[t][15];
            }
            __syncthreads();
        }

        // candidate filter (tile0 uses <= T0, later tiles < running 16th)
        if (active) {
            #pragma unroll
            for (int r = 0; r < DR; ++r) {
                float thr = thrS[r];
                #pragma unroll
                for (int q = 0; q < 4; ++q) {
                    float v = dv[r][q];
                    bool take = (tile == 0) ? (v <= thr) : (v < thr);
                    if (take) {
                        int p = atomicAdd(&candC[r], 1);
                        if (p < 192) candV[r][p] = v;
                    }
                }
            }
        }
        __syncthreads();

        // owner threads insert candidates (order-independent, exact)
        if (t < DR) {
            int cnt = candC[t];
            if (cnt > 192) cnt = 192;
            for (int qq = 0; qq < cnt; ++qq) {
                float v = candV[t][qq];
                if (v < s16[t][15]) {
                    int pos = 15;
                    while (pos > 0 && s16[t][pos - 1] > v) {
                        s16[t][pos] = s16[t][pos - 1];
                        --pos;
                    }
                    s16[t][pos] = v;
                }
            }
            candC[t] = 0;
            thrS[t] = s16[t][15];
        }
        __syncthreads();
    }

    // rowmax reduce + density
    #pragma unroll
    for (int r = 0; r < DR; ++r) minb[r][t] = rm[r];
    __syncthreads();
    if (t < DR) {
        float mx = -FLT_MAX;
        for (int e = 0; e < 256; ++e) mx = fmaxf(mx, minb[t][e]);
        rowmax[b * N + i0 + t] = mx;

        // numpy pairwise fp32 sum of the 16 ascending values
        float r8[8];
        #pragma unroll
        for (int j2 = 0; j2 < 8; ++j2) r8[j2] = s16[t][j2] + s16[t][8 + j2];
        float s = ((r8[0] + r8[1]) + (r8[2] + r8[3]))
                + ((r8[4] + r8[5]) + (r8[6] + r8[7]));
        float mean = s * (1.0f / 16.0f);
        densbits[b * N + i0 + t] = f32q_ftz(exp(-(double)mean));
    }
}

// ---------------------------------------------------------------------------
// K2: per-batch global max of d (fp32)
__global__ __launch_bounds__(256) void k_dmax(const float* __restrict__ rowmax,
                                              float* __restrict__ dmax) {
    int b = blockIdx.x, t = threadIdx.x;
    __shared__ float rv[256];
    float lm = -FLT_MAX;
    for (int j = t; j < N; j += 256) lm = fmaxf(lm, rowmax[b * N + j]);
    rv[t] = lm;
    __syncthreads();
    for (int s = 128; s > 0; s >>= 1) {
        if (t < s) rv[t] = fmaxf(rv[t], rv[t + s]);
        __syncthreads();
    }
    if (t == 0) dmax[b] = rv[0];
}

// ---------------------------------------------------------------------------
// K3: dist_peak = min over j with dens[j] > dens[i] of d[i,j] (else dmax);
// score = fp32(dist_peak * density) emulated exactly; packed rank key.
__global__ __launch_bounds__(256) void k_score(const float* __restrict__ y,
                                               const float* __restrict__ rel,
                                               const float* __restrict__ ynorm,
                                               const uint32_t* __restrict__ densbits,
                                               const float* __restrict__ dmax,
                                               unsigned long long* __restrict__ keys) {
    const int i = blockIdx.x;
    const int b = blockIdx.y;
    const int t = threadIdx.x;

    const uint32_t bi = densbits[b * N + i];
    if (bi == 0u) {   // score == +0.0 exactly; key = (0, ~idx)
        if (t == 0) keys[b * N + i] =
            (unsigned long long)(0xFFFFFFFFu - (uint32_t)i);
        return;
    }

    __shared__ float yi[C];
    __shared__ float rv[256];

    const float* yb = y + (size_t)b * C * N;
    if (t < C) yi[t] = yb[(size_t)t * N + i];
    __syncthreads();

    const float ni = ynorm[b * N + i];
    float mn = FLT_MAX;
    for (int j = t; j < N; j += 256) {
        if (densbits[b * N + j] > bi) {
            const float* p = yb + j;
            float dot = 0.f;
            #pragma unroll 8
            for (int c = 0; c < C; ++c) dot += yi[c] * p[(size_t)c * N];
            float d = ni + ynorm[b * N + j] - 2.f * dot + rel[(size_t)i * N + j];
            mn = fminf(mn, d);
        }
    }
    rv[t] = mn;
    __syncthreads();
    for (int s = 128; s > 0; s >>= 1) {
        if (t < s) rv[t] = fminf(rv[t], rv[t + s]);
        __syncthreads();
    }
    if (t == 0) {
        float dp = fminf(rv[0], dmax[b]);
        double p = (double)dp * (double)__uint_as_float(bi);
        float sf = (float)p;
        uint32_t sb = (sf < 0x1p-126f) ? 0u : __float_as_uint(sf);
        keys[b * N + i] = ((unsigned long long)sb << 32)
                        | (unsigned long long)(0xFFFFFFFFu - (uint32_t)i);
    }
}

// ---------------------------------------------------------------------------
// K4: per-batch bitonic sort of packed keys, descending -> top M indices.
__global__ __launch_bounds__(512) void k_topm(const unsigned long long* __restrict__ keys,
                                              int* __restrict__ sidx) {
    constexpr int SZ = 4096;
    int b = blockIdx.x, t = threadIdx.x;
    __shared__ unsigned long long ks[SZ];
    for (int i = t; i < SZ; i += 512) ks[i] = (i < N) ? keys[b * N + i] : 0ull;
    __syncthreads();
    for (int k = 2; k <= SZ; k <<= 1) {
        for (int j = k >> 1; j > 0; j >>= 1) {
            for (int i = t; i < SZ; i += 512) {
                int ixj = i ^ j;
                if (ixj > i) {
                    bool up = ((i & k) == 0);
                    unsigned long long a = ks[i], c2 = ks[ixj];
                    bool doSwap = up ? (a < c2) : (a > c2);  // descending
                    if (doSwap) { ks[i] = c2; ks[ixj] = a; }
                }
            }
            __syncthreads();
        }
    }
    for (int m = t; m < M; m += 512)
        sidx[b * M + m] = (int)(0xFFFFFFFFu - (uint32_t)(ks[m] & 0xFFFFFFFFull));
}

// ---------------------------------------------------------------------------
// K5 v2: gather centers TRANSPOSED: cenT[b][c][m] = y[b][c][sidx[m]].
__global__ __launch_bounds__(256) void k_cen(const float* __restrict__ y,
                                             const int* __restrict__ sidx,
                                             const float* __restrict__ ynorm,
                                             float* __restrict__ cenT,
                                             float* __restrict__ cnorm) {
    const int b = blockIdx.y;
    const int m = blockIdx.x * 256 + threadIdx.x;
    if (m >= M) return;
    const int j = sidx[b * M + m];
    cnorm[b * M + m] = ynorm[b * N + j];
    const float* yb = y + (size_t)b * C * N;
    float* ct = cenT + (size_t)b * C * M;
    #pragma unroll 8
    for (int c = 0; c < C; ++c)
        ct[(size_t)c * M + m] = yb[(size_t)c * N + j];
}

// ---------------------------------------------------------------------------
// K6 v2 (validated round 8): tiled assignment GEMM + softmax + top-5.
__global__ __launch_bounds__(256) void k_assign(const float* __restrict__ x,
                                                const float* __restrict__ cenT,
                                                const float* __restrict__ xnorm,
                                                const float* __restrict__ cnorm,
                                                float* __restrict__ assign,
                                                int* __restrict__ nnidx) {
    const int b  = blockIdx.y;
    const int i0 = blockIdx.x * 8;
    const int t  = threadIdx.x;

    __shared__ __align__(16) float xiS[8][100];
    __shared__ __align__(16) float Ss[8][788];
    __shared__ float xnS[8];

    const float* xb = x + (size_t)b * C * N;
    const float* ct = cenT + (size_t)b * C * M;

    for (int e = t; e < C * 2; e += 256) {
        int c = e >> 1, n4 = (e & 1) << 2;
        float4 v = *reinterpret_cast<const float4*>(xb + (size_t)c * N + i0 + n4);
        xiS[n4 + 0][c] = v.x;
        xiS[n4 + 1][c] = v.y;
        xiS[n4 + 2][c] = v.z;
        xiS[n4 + 3][c] = v.w;
    }
    if (t < 8) xnS[t] = xnorm[b * N + i0 + t];
    __syncthreads();

    if (t < 196) {
        const int mt = 4 * t;
        float acc[8][4];
        #pragma unroll
        for (int r = 0; r < 8; ++r)
            #pragma unroll
            for (int q = 0; q < 4; ++q) acc[r][q] = 0.f;

        for (int c0 = 0; c0 < C; c0 += 4) {
            float4 bq0 = *reinterpret_cast<const float4*>(ct + (size_t)(c0 + 0) * M + mt);
            float4 bq1 = *reinterpret_cast<const float4*>(ct + (size_t)(c0 + 1) * M + mt);
            float4 bq2 = *reinterpret_cast<const float4*>(ct + (size_t)(c0 + 2) * M + mt);
            float4 bq3 = *reinterpret_cast<const float4*>(ct + (size_t)(c0 + 3) * M + mt);
            #pragma unroll
            for (int r = 0; r < 8; ++r) {
                float4 a4 = *reinterpret_cast<const float4*>(&xiS[r][c0]);
                acc[r][0] += a4.x * bq0.x; acc[r][1] += a4.x * bq0.y;
                acc[r][2] += a4.x * bq0.z; acc[r][3] += a4.x * bq0.w;
                acc[r][0] += a4.y * bq1.x; acc[r][1] += a4.y * bq1.y;
                acc[r][2] += a4.y * bq1.z; acc[r][3] += a4.y * bq1.w;
                acc[r][0] += a4.z * bq2.x; acc[r][1] += a4.z * bq2.y;
                acc[r][2] += a4.z * bq2.z; acc[r][3] += a4.z * bq2.w;
                acc[r][0] += a4.w * bq3.x; acc[r][1] += a4.w * bq3.y;
                acc[r][2] += a4.w * bq3.z; acc[r][3] += a4.w * bq3.w;
            }
        }

        float4 cn4 = *reinterpret_cast<const float4*>(cnorm + (size_t)b * M + mt);
        float cn[4] = {cn4.x, cn4.y, cn4.z, cn4.w};
        #pragma unroll
        for (int r = 0; r < 8; ++r) {
            float xn = xnS[r];
            float sv[4];
            #pragma unroll
            for (int q = 0; q < 4; ++q)
                sv[q] = -(xn + cn[q] - 2.f * acc[r][q]);
            *reinterpret_cast<float4*>(&Ss[r][mt]) =
                make_float4(sv[0], sv[1], sv[2], sv[3]);
        }
    }
    __syncthreads();

    const int r = t >> 5;
    const int l = t & 31;

    float lm = -FLT_MAX;
    for (int m = l; m < M; m += 32) lm = fmaxf(lm, Ss[r][m]);
    #pragma unroll
    for (int off = 16; off > 0; off >>= 1)
        lm = fmaxf(lm, __shfl_xor(lm, off, 32));
    const float smax = lm;

    float ls = 0.f;
    for (int m = l; m < M; m += 32) ls += expf(Ss[r][m] - smax);
    #pragma unroll
    for (int off = 16; off > 0; off >>= 1)
        ls += __shfl_xor(ls, off, 32);
    const float inv = 1.f / ls;

    float* arow = assign + ((size_t)b * N + i0 + r) * M;
    for (int m = l; m < M; m += 32) arow[m] = expf(Ss[r][m] - smax) * inv;

    for (int round = 0; round < TK; ++round) {
        float lv = -FLT_MAX; int li = M;
        for (int m = l; m < M; m += 32) {
            float v = Ss[r][m];
            if (v > lv) { lv = v; li = m; }
        }
        #pragma unroll
        for (int off = 16; off > 0; off >>= 1) {
            float ov = __shfl_xor(lv, off, 32);
            int   oi = __shfl_xor(li, off, 32);
            if (ov > lv || (ov == lv && oi < li)) { lv = ov; li = oi; }
        }
        if (l == 0) {
            nnidx[((size_t)b * N + i0 + r) * TK + round] = li;
            Ss[r][li] = -FLT_MAX;
        }
        __syncthreads();
    }
}

// ---------------------------------------------------------------------------
// K7: agg[b,m,c] = (sum_n assign[n,m] * x[c,n]) / (mass_m + 1e-6)
__global__ __launch_bounds__(256) void k_agg(const float* __restrict__ assign,
                                             const float* __restrict__ x,
                                             float* __restrict__ aggws) {
    const int b = blockIdx.y;
    const int m0 = blockIdx.x * 16;
    const int t = threadIdx.x;
    __shared__ float As[64][16];
    __shared__ float Xs[96][65];
    __shared__ float minv[16];

    float acc[6] = {0.f, 0.f, 0.f, 0.f, 0.f, 0.f};
    float massacc = 0.f;

    for (int n0 = 0; n0 < N; n0 += 64) {
        for (int e = t; e < 64 * 16; e += 256) {
            int nn = e >> 4, mm = e & 15;
            As[nn][mm] = assign[((size_t)b * N + n0 + nn) * M + m0 + mm];
        }
        for (int e = t; e < 96 * 64; e += 256) {
            int c = e >> 6, nn = e & 63;
            Xs[c][nn] = x[((size_t)b * C + c) * N + n0 + nn];
        }
        __syncthreads();
        if (t < 16) {
            #pragma unroll
            for (int nn = 0; nn < 64; ++nn) massacc += As[nn][t];
        }
        #pragma unroll
        for (int u = 0; u < 6; ++u) {
            int e = t + u * 256;
            int mm = e & 15, c = e >> 4;
            float a = acc[u];
            #pragma unroll 8
            for (int nn = 0; nn < 64; ++nn) a += As[nn][mm] * Xs[c][nn];
            acc[u] = a;
        }
        __syncthreads();
    }
    if (t < 16) minv[t] = 1.f / (massacc + 1e-6f);
    __syncthreads();
    #pragma unroll
    for (int u = 0; u < 6; ++u) {
        int e = t + u * 256;
        int mm = e & 15, c = e >> 4;
        aggws[((size_t)b * M + m0 + mm) * C + c] = acc[u] * minv[mm];
    }
}

// ---------------------------------------------------------------------------
// K8: per-center FFN with residual; writes updated agg (ws) and `refined`
__global__ __launch_bounds__(128) void k_ffn(const float* __restrict__ w1,
                                             const float* __restrict__ b1,
                                             const float* __restrict__ g1,
                                             const float* __restrict__ bt1,
                                             const float* __restrict__ w2,
                                             const float* __restrict__ b2,
                                             const float* __restrict__ g2,
                                             const float* __restrict__ bt2,
                                             float* __restrict__ aggws,
                                             float* __restrict__ refined) {
    const int m = blockIdx.x;
    const int b = blockIdx.y;
    const int t = threadIdx.x;
    __shared__ float ar[C];
    __shared__ float hd[C4];

    if (t < C) ar[t] = aggws[((size_t)b * M + m) * C + t];
    __syncthreads();

    for (int o = t; o < C4; o += 128) {
        const float* w = w1 + (size_t)o * C;
        float h = b1[o];
        #pragma unroll 8
        for (int c = 0; c < C; ++c) h += w[c] * ar[c];
        h = h * g1[o] + bt1[o];
        hd[o] = fmaxf(h, 0.f);
    }
    __syncthreads();

    if (t < C) {
        const float* w = w2 + (size_t)t * C4;
        float f = b2[t];
        #pragma unroll 8
        for (int o = 0; o < C4; ++o) f += w[o] * hd[o];
        float v = ar[t] + (f * g2[t] + bt2[t]);
        aggws[((size_t)b * M + m) * C + t] = v;
        refined[((size_t)b * C + t) * M + m] = v;
    }
}

// ---------------------------------------------------------------------------
// K9: rel = max over top-5 agg rows - xf; interleaved xcat;
// out = relu((nn_w @ xcat + nn_b) * g + bt), stored (B, OUT, N)
__global__ __launch_bounds__(256) void k_final(const float* __restrict__ x,
                                               const float* __restrict__ aggws,
                                               const int* __restrict__ nnidx,
                                               const float* __restrict__ nnw,
                                               const float* __restrict__ nnb,
                                               const float* __restrict__ nng,
                                               const float* __restrict__ nnbt,
                                               float* __restrict__ out) {
    const int b = blockIdx.y;
    const int n0 = blockIdx.x * 16;
    const int t = threadIdx.x;
    __shared__ float xc[16][193];
    __shared__ int nid[16 * TK];

    if (t < 16 * TK) nid[t] = nnidx[((size_t)b * N + n0) * TK + t];
    __syncthreads();

    for (int e = t; e < C * 16; e += 256) {
        int c = e >> 4, r = e & 15;
        float xv = x[((size_t)b * C + c) * N + n0 + r];
        float mx = -FLT_MAX;
        #pragma unroll
        for (int k = 0; k < TK; ++k) {
            int j = nid[r * TK + k];
            mx = fmaxf(mx, aggws[((size_t)b * M + j) * C + c]);
        }
        xc[r][2 * c]     = xv;
        xc[r][2 * c + 1] = mx - xv;
    }
    __syncthreads();

    const int r = t & 15;
    const int og = t >> 4;
    #pragma unroll
    for (int oo = 0; oo < 12; ++oo) {
        int o = og + (oo << 4);
        const float* w = nnw + (size_t)o * (2 * C);
        float a = nnb[o];
        #pragma unroll 8
        for (int cc = 0; cc < 2 * C; ++cc) a += w[cc] * xc[r][cc];
        a = a * nng[o] + nnbt[o];
        out[((size_t)b * OUT + o) * N + n0 + r] = fmaxf(a, 0.f);
    }
}

// ---------------------------------------------------------------------------
extern "C" void kernel_launch(void* const* d_in, const int* in_sizes, int n_in,
                              void* d_out, int out_size, void* d_ws, size_t ws_size,
                              hipStream_t stream) {
    const float* x    = (const float*)d_in[0];
    const float* rel  = (const float*)d_in[1];
    const float* y    = (const float*)d_in[2];
    const float* w1   = (const float*)d_in[3];
    const float* b1   = (const float*)d_in[4];
    const float* g1   = (const float*)d_in[5];
    const float* bt1  = (const float*)d_in[6];
    const float* w2   = (const float*)d_in[7];
    const float* b2   = (const float*)d_in[8];
    const float* g2   = (const float*)d_in[9];
    const float* bt2  = (const float*)d_in[10];
    const float* nnw  = (const float*)d_in[11];
    const float* nnb  = (const float*)d_in[12];
    const float* nng  = (const float*)d_in[13];
    const float* nnbt = (const float*)d_in[14];

    float* out     = (float*)d_out;
    float* refined = out + (size_t)B * OUT * N;

    char* w = (char*)d_ws;
    auto alloc = [&](size_t nbytes) -> void* {
        void* p = (void*)w;
        w += (nbytes + 255) & ~(size_t)255;
        return p;
    };
    float*    ynorm    = (float*)   alloc((size_t)B * N * 4);
    float*    xnorm    = (float*)   alloc((size_t)B * N * 4);
    uint32_t* densbits = (uint32_t*)alloc((size_t)B * N * 4);
    float*    rowmax   = (float*)   alloc((size_t)B * N * 4);
    float*    dmaxv    = (float*)   alloc((size_t)B * 4);
    unsigned long long* keys = (unsigned long long*)alloc((size_t)B * N * 8);
    int*      sidx     = (int*)     alloc((size_t)B * M * 4);
    float*    cnorm    = (float*)   alloc((size_t)B * M * 4);
    float*    cenT     = (float*)   alloc((size_t)B * C * M * 4);
    float*    aggws    = (float*)   alloc((size_t)B * M * C * 4);
    int*      nnidx    = (int*)     alloc((size_t)B * N * TK * 4);
    float*    assign   = (float*)   alloc((size_t)B * N * M * 4);

    k_norms<<<dim3((B * N + 255) / 256), dim3(256), 0, stream>>>(y, x, ynorm, xnorm);
    k_density<<<dim3(N / DR, B), dim3(256), 0, stream>>>(y, rel, ynorm, densbits, rowmax);
    k_dmax<<<dim3(B), dim3(256), 0, stream>>>(rowmax, dmaxv);
    k_score<<<dim3(N, B), dim3(256), 0, stream>>>(y, rel, ynorm, densbits, dmaxv, keys);
    k_topm<<<dim3(B), dim3(512), 0, stream>>>(keys, sidx);
    k_cen<<<dim3((M + 255) / 256, B), dim3(256), 0, stream>>>(y, sidx, ynorm, cenT, cnorm);
    k_assign<<<dim3(N / 8, B), dim3(256), 0, stream>>>(x, cenT, xnorm, cnorm, assign, nnidx);
    k_agg<<<dim3(M / 16, B), dim3(256), 0, stream>>>(assign, x, aggws);
    k_ffn<<<dim3(M, B), dim3(128), 0, stream>>>(w1, b1, g1, bt1, w2, b2, g2, bt2, aggws, refined);
    k_final<<<dim3(N / 16, B), dim3(256), 0, stream>>>(x, aggws, nnidx, nnw, nnb, nng, nnbt, out);
}

// Round 11
// 1447.732 us; speedup vs baseline: 1.4348x; 1.2442x over previous
//
#include <hip/hip_runtime.h>
#include <float.h>
#include <math.h>
#include <stdint.h>

// Problem constants (match reference)
constexpr int B   = 8;
constexpr int C   = 96;
constexpr int N   = 3136;   // 56*56
constexpr int M   = 784;    // RATIO*N
constexpr int C4  = 384;    // 4*C
constexpr int OUT = 192;
constexpr int KD  = 16;     // K_DPC
constexpr int TK  = 5;      // TOPK

// ---------------------------------------------------------------------------
// fp32 round-to-nearest of a positive double WITH flush-to-zero of subnormal
// results (validated semantics for the reference's exp underflow).
__device__ inline uint32_t f32q_ftz(double t) {
    if (t <= 0.0) return 0u;
    float f = (float)t;              // exact RN cvt (double->float)
    if (f < 0x1p-126f) return 0u;    // subnormal result -> flush to zero
    return __float_as_uint(f);
}

// ---------------------------------------------------------------------------
// K0: per-point squared norms of y and x (both laid out (B,C,N))
__global__ __launch_bounds__(256) void k_norms(const float* __restrict__ y,
                                               const float* __restrict__ x,
                                               float* __restrict__ ynorm,
                                               float* __restrict__ xnorm) {
    int id = blockIdx.x * 256 + threadIdx.x;
    if (id >= B * N) return;
    int b = id / N, n = id % N;
    const float* yb = y + (size_t)b * C * N + n;
    const float* xb = x + (size_t)b * C * N + n;
    float sy = 0.f, sx = 0.f;
    #pragma unroll 8
    for (int c = 0; c < C; ++c) {
        float a = yb[(size_t)c * N]; sy += a * a;
        float d = xb[(size_t)c * N]; sx += d * d;
    }
    ynorm[id] = sy;
    xnorm[id] = sx;
}

// ---------------------------------------------------------------------------
// K-TR: tiled transpose of y and x into [b][n][c] layout (for wave-uniform
// A-panel reads). 32x32 tiles, padded LDS.
__global__ __launch_bounds__(256) void k_tr(const float* __restrict__ y,
                                            const float* __restrict__ x,
                                            float* __restrict__ yT,
                                            float* __restrict__ xT) {
    __shared__ float ty[32][33];
    __shared__ float tx[32][33];
    const int b  = blockIdx.z;
    const int n0 = blockIdx.x * 32;
    const int c0 = blockIdx.y * 32;
    const int tn = threadIdx.x & 31;
    const int tc = threadIdx.x >> 5;   // 0..7
    #pragma unroll
    for (int k = 0; k < 4; ++k) {
        int c = c0 + tc + 8 * k;
        ty[tc + 8 * k][tn] = y[((size_t)b * C + c) * N + n0 + tn];
        tx[tc + 8 * k][tn] = x[((size_t)b * C + c) * N + n0 + tn];
    }
    __syncthreads();
    #pragma unroll
    for (int k = 0; k < 4; ++k) {
        int n = n0 + tc + 8 * k;
        yT[((size_t)b * N + n) * C + c0 + tn] = ty[tn][tc + 8 * k];
        xT[((size_t)b * N + n) * C + c0 + tn] = tx[tn][tc + 8 * k];
    }
}

constexpr int DR = 8;       // rows per block
constexpr int DCOLS = 1024; // cols per tile

// ---------------------------------------------------------------------------
// K1 v7 (yT path): A-fragments read directly from yT with wave-uniform
// addresses (no LDS staging, no ds_reads). Tile-0 threshold + rowmax are
// 32-lane-per-row parallel reductions (value-multiset exact). Candidate
// filter/insert and all arithmetic identical to the validated v6.
__global__ __launch_bounds__(256) void k_density_t(const float* __restrict__ y,
                                                   const float* __restrict__ yT,
                                                   const float* __restrict__ rel,
                                                   const float* __restrict__ ynorm,
                                                   uint32_t* __restrict__ densbits,
                                                   float* __restrict__ rowmax) {
    const int b  = blockIdx.y;
    const int i0 = blockIdx.x * DR;
    const int t  = threadIdx.x;
    const int gr = t >> 5;      // row group 0..7
    const int gl = t & 31;      // lane in group

    __shared__ float niS[DR];
    __shared__ float s16[DR][17];
    __shared__ float thrS[DR];
    __shared__ float minb[DR][257];
    __shared__ float candV[DR][193];
    __shared__ int   candC[DR];

    const float* yb  = y  + (size_t)b * C * N;
    const float* yTb = yT + (size_t)b * N * C;

    if (t < DR) {
        niS[t] = ynorm[b * N + i0 + t];
        thrS[t] = FLT_MAX;
        candC[t] = 0;
        #pragma unroll
        for (int q = 0; q < 16; ++q) s16[t][q] = FLT_MAX;
    }
    float rm[DR];
    #pragma unroll
    for (int r = 0; r < DR; ++r) rm[r] = -FLT_MAX;
    __syncthreads();

    for (int tile = 0; tile < 4; ++tile) {
        const int jt = tile * DCOLS + 4 * t;
        const bool active = (jt < N);

        float dv[DR][4];

        if (active) {
            float acc[DR][4];
            #pragma unroll
            for (int r = 0; r < DR; ++r)
                #pragma unroll
                for (int q = 0; q < 4; ++q) acc[r][q] = 0.f;

            for (int c0 = 0; c0 < C; c0 += 4) {
                float4 bq0 = *reinterpret_cast<const float4*>(yb + (size_t)(c0 + 0) * N + jt);
                float4 bq1 = *reinterpret_cast<const float4*>(yb + (size_t)(c0 + 1) * N + jt);
                float4 bq2 = *reinterpret_cast<const float4*>(yb + (size_t)(c0 + 2) * N + jt);
                float4 bq3 = *reinterpret_cast<const float4*>(yb + (size_t)(c0 + 3) * N + jt);
                #pragma unroll
                for (int r = 0; r < DR; ++r) {
                    float4 a4 = *reinterpret_cast<const float4*>(
                        yTb + (size_t)(i0 + r) * C + c0);   // wave-uniform addr
                    // sequential c accumulation order (c0, c0+1, c0+2, c0+3)
                    acc[r][0] += a4.x * bq0.x; acc[r][1] += a4.x * bq0.y;
                    acc[r][2] += a4.x * bq0.z; acc[r][3] += a4.x * bq0.w;
                    acc[r][0] += a4.y * bq1.x; acc[r][1] += a4.y * bq1.y;
                    acc[r][2] += a4.y * bq1.z; acc[r][3] += a4.y * bq1.w;
                    acc[r][0] += a4.z * bq2.x; acc[r][1] += a4.z * bq2.y;
                    acc[r][2] += a4.z * bq2.z; acc[r][3] += a4.z * bq2.w;
                    acc[r][0] += a4.w * bq3.x; acc[r][1] += a4.w * bq3.y;
                    acc[r][2] += a4.w * bq3.z; acc[r][3] += a4.w * bq3.w;
                }
            }

            float4 yn4 = *reinterpret_cast<const float4*>(ynorm + (size_t)b * N + jt);
            float yn[4] = {yn4.x, yn4.y, yn4.z, yn4.w};
            #pragma unroll
            for (int r = 0; r < DR; ++r) {
                float4 rl4 = *reinterpret_cast<const float4*>(rel + (size_t)(i0 + r) * N + jt);
                float rl[4] = {rl4.x, rl4.y, rl4.z, rl4.w};
                float niv = niS[r];
                #pragma unroll
                for (int q = 0; q < 4; ++q)
                    dv[r][q] = niv + yn[q] - 2.f * acc[r][q] + rl[q];
                rm[r] = fmaxf(rm[r],
                        fmaxf(fmaxf(dv[r][0], dv[r][1]), fmaxf(dv[r][2], dv[r][3])));
            }
        }

        if (tile == 0) {
            #pragma unroll
            for (int r = 0; r < DR; ++r) {
                float mn = active
                    ? fminf(fminf(dv[r][0], dv[r][1]), fminf(dv[r][2], dv[r][3]))
                    : FLT_MAX;
                minb[r][t] = mn;
            }
            __syncthreads();
            // parallel exact 16th-smallest of the 256 minima (per row group)
            {
                float t16 = FLT_MAX;
                for (int round = 0; round < 16; ++round) {
                    float lv = FLT_MAX; int li = 0x7fffffff;
                    #pragma unroll
                    for (int e = 0; e < 8; ++e) {
                        int idx = gl * 8 + e;
                        float v = minb[gr][idx];
                        if (v < lv) { lv = v; li = idx; }
                    }
                    #pragma unroll
                    for (int off = 16; off > 0; off >>= 1) {
                        float ov = __shfl_xor(lv, off, 32);
                        int   oi = __shfl_xor(li, off, 32);
                        if (ov < lv || (ov == lv && oi < li)) { lv = ov; li = oi; }
                    }
                    if ((li >> 3) == gl) minb[gr][li] = FLT_MAX;
                    t16 = lv;
                }
                if (gl == 0) thrS[gr] = t16;
            }
            __syncthreads();
        }

        // candidate filter (tile0 uses <= T0, later tiles < running 16th)
        if (active) {
            #pragma unroll
            for (int r = 0; r < DR; ++r) {
                float thr = thrS[r];
                #pragma unroll
                for (int q = 0; q < 4; ++q) {
                    float v = dv[r][q];
                    bool take = (tile == 0) ? (v <= thr) : (v < thr);
                    if (take) {
                        int p = atomicAdd(&candC[r], 1);
                        if (p < 192) candV[r][p] = v;
                    }
                }
            }
        }
        __syncthreads();

        // owner threads insert candidates (order-independent, exact)
        if (t < DR) {
            int cnt = candC[t];
            if (cnt > 192) cnt = 192;
            for (int qq = 0; qq < cnt; ++qq) {
                float v = candV[t][qq];
                if (v < s16[t][15]) {
                    int pos = 15;
                    while (pos > 0 && s16[t][pos - 1] > v) {
                        s16[t][pos] = s16[t][pos - 1];
                        --pos;
                    }
                    s16[t][pos] = v;
                }
            }
            candC[t] = 0;
            thrS[t] = s16[t][15];
        }
        __syncthreads();
    }

    // rowmax: parallel per-row-group reduction
    #pragma unroll
    for (int r = 0; r < DR; ++r) minb[r][t] = rm[r];
    __syncthreads();
    {
        float mx = -FLT_MAX;
        #pragma unroll
        for (int e = 0; e < 8; ++e) mx = fmaxf(mx, minb[gr][gl * 8 + e]);
        #pragma unroll
        for (int off = 16; off > 0; off >>= 1)
            mx = fmaxf(mx, __shfl_xor(mx, off, 32));
        if (gl == 0) {
            rowmax[b * N + i0 + gr] = mx;
            // numpy pairwise fp32 sum of the 16 ascending values
            float r8[8];
            #pragma unroll
            for (int j2 = 0; j2 < 8; ++j2) r8[j2] = s16[gr][j2] + s16[gr][8 + j2];
            float s = ((r8[0] + r8[1]) + (r8[2] + r8[3]))
                    + ((r8[4] + r8[5]) + (r8[6] + r8[7]));
            float mean = s * (1.0f / 16.0f);
            densbits[b * N + i0 + gr] = f32q_ftz(exp(-(double)mean));
        }
    }
}

// ---------------------------------------------------------------------------
// K1 v6 (fallback, validated round 10)
__global__ __launch_bounds__(256) void k_density(const float* __restrict__ y,
                                                 const float* __restrict__ rel,
                                                 const float* __restrict__ ynorm,
                                                 uint32_t* __restrict__ densbits,
                                                 float* __restrict__ rowmax) {
    const int b  = blockIdx.y;
    const int i0 = blockIdx.x * DR;
    const int t  = threadIdx.x;

    __shared__ __align__(16) float yiS[DR][100];
    __shared__ float niS[DR];
    __shared__ float s16[DR][17];
    __shared__ float thrS[DR];
    __shared__ float minb[DR][257];
    __shared__ float candV[DR][193];
    __shared__ int   candC[DR];

    const float* yb = y + (size_t)b * C * N;

    for (int e = t; e < C * 2; e += 256) {
        int c = e >> 1, n4 = (e & 1) << 2;
        float4 v = *reinterpret_cast<const float4*>(yb + (size_t)c * N + i0 + n4);
        yiS[n4 + 0][c] = v.x;
        yiS[n4 + 1][c] = v.y;
        yiS[n4 + 2][c] = v.z;
        yiS[n4 + 3][c] = v.w;
    }
    if (t < DR) {
        niS[t] = ynorm[b * N + i0 + t];
        thrS[t] = FLT_MAX;
        candC[t] = 0;
        #pragma unroll
        for (int q = 0; q < 16; ++q) s16[t][q] = FLT_MAX;
    }
    float rm[DR];
    #pragma unroll
    for (int r = 0; r < DR; ++r) rm[r] = -FLT_MAX;
    __syncthreads();

    for (int tile = 0; tile < 4; ++tile) {
        const int jt = tile * DCOLS + 4 * t;
        const bool active = (jt < N);

        float acc[DR][4];
        #pragma unroll
        for (int r = 0; r < DR; ++r)
            #pragma unroll
            for (int q = 0; q < 4; ++q) acc[r][q] = 0.f;

        float dv[DR][4];

        if (active) {
            for (int c0 = 0; c0 < C; c0 += 4) {
                float4 bq0 = *reinterpret_cast<const float4*>(yb + (size_t)(c0 + 0) * N + jt);
                float4 bq1 = *reinterpret_cast<const float4*>(yb + (size_t)(c0 + 1) * N + jt);
                float4 bq2 = *reinterpret_cast<const float4*>(yb + (size_t)(c0 + 2) * N + jt);
                float4 bq3 = *reinterpret_cast<const float4*>(yb + (size_t)(c0 + 3) * N + jt);
                #pragma unroll
                for (int r = 0; r < DR; ++r) {
                    float4 a4 = *reinterpret_cast<const float4*>(&yiS[r][c0]);
                    acc[r][0] += a4.x * bq0.x; acc[r][1] += a4.x * bq0.y;
                    acc[r][2] += a4.x * bq0.z; acc[r][3] += a4.x * bq0.w;
                    acc[r][0] += a4.y * bq1.x; acc[r][1] += a4.y * bq1.y;
                    acc[r][2] += a4.y * bq1.z; acc[r][3] += a4.y * bq1.w;
                    acc[r][0] += a4.z * bq2.x; acc[r][1] += a4.z * bq2.y;
                    acc[r][2] += a4.z * bq2.z; acc[r][3] += a4.z * bq2.w;
                    acc[r][0] += a4.w * bq3.x; acc[r][1] += a4.w * bq3.y;
                    acc[r][2] += a4.w * bq3.z; acc[r][3] += a4.w * bq3.w;
                }
            }

            float4 yn4 = *reinterpret_cast<const float4*>(ynorm + (size_t)b * N + jt);
            float yn[4] = {yn4.x, yn4.y, yn4.z, yn4.w};
            #pragma unroll
            for (int r = 0; r < DR; ++r) {
                float4 rl4 = *reinterpret_cast<const float4*>(rel + (size_t)(i0 + r) * N + jt);
                float rl[4] = {rl4.x, rl4.y, rl4.z, rl4.w};
                float niv = niS[r];
                #pragma unroll
                for (int q = 0; q < 4; ++q)
                    dv[r][q] = niv + yn[q] - 2.f * acc[r][q] + rl[q];
                rm[r] = fmaxf(rm[r],
                        fmaxf(fmaxf(dv[r][0], dv[r][1]), fmaxf(dv[r][2], dv[r][3])));
            }
        }

        if (tile == 0) {
            #pragma unroll
            for (int r = 0; r < DR; ++r) {
                float mn = active
                    ? fminf(fminf(dv[r][0], dv[r][1]), fminf(dv[r][2], dv[r][3]))
                    : FLT_MAX;
                minb[r][t] = mn;
            }
            __syncthreads();
            if (t < DR) {
                #pragma unroll
                for (int q = 0; q < 16; ++q) candV[t][q] = FLT_MAX;
                for (int e = 0; e < 256; ++e) {
                    float v = minb[t][e];
                    if (v < candV[t][15]) {
                        int pos = 15;
                        while (pos > 0 && candV[t][pos - 1] > v) {
                            candV[t][pos] = candV[t][pos - 1];
                            --pos;
                        }
                        candV[t][pos] = v;
                    }
                }
                thrS[t] = candV[t][15];
            }
            __syncthreads();
        }

        if (active) {
            #pragma unroll
            for (int r = 0; r < DR; ++r) {
                float thr = thrS[r];
                #pragma unroll
                for (int q = 0; q < 4; ++q) {
                    float v = dv[r][q];
                    bool take = (tile == 0) ? (v <= thr) : (v < thr);
                    if (take) {
                        int p = atomicAdd(&candC[r], 1);
                        if (p < 192) candV[r][p] = v;
                    }
                }
            }
        }
        __syncthreads();

        if (t < DR) {
            int cnt = candC[t];
            if (cnt > 192) cnt = 192;
            for (int qq = 0; qq < cnt; ++qq) {
                float v = candV[t][qq];
                if (v < s16[t][15]) {
                    int pos = 15;
                    while (pos > 0 && s16[t][pos - 1] > v) {
                        s16[t][pos] = s16[t][pos - 1];
                        --pos;
                    }
                    s16[t][pos] = v;
                }
            }
            candC[t] = 0;
            thrS[t] = s16[t][15];
        }
        __syncthreads();
    }

    #pragma unroll
    for (int r = 0; r < DR; ++r) minb[r][t] = rm[r];
    __syncthreads();
    if (t < DR) {
        float mx = -FLT_MAX;
        for (int e = 0; e < 256; ++e) mx = fmaxf(mx, minb[t][e]);
        rowmax[b * N + i0 + t] = mx;

        float r8[8];
        #pragma unroll
        for (int j2 = 0; j2 < 8; ++j2) r8[j2] = s16[t][j2] + s16[t][8 + j2];
        float s = ((r8[0] + r8[1]) + (r8[2] + r8[3]))
                + ((r8[4] + r8[5]) + (r8[6] + r8[7]));
        float mean = s * (1.0f / 16.0f);
        densbits[b * N + i0 + t] = f32q_ftz(exp(-(double)mean));
    }
}

// ---------------------------------------------------------------------------
// K2: per-batch global max of d (fp32)
__global__ __launch_bounds__(256) void k_dmax(const float* __restrict__ rowmax,
                                              float* __restrict__ dmax) {
    int b = blockIdx.x, t = threadIdx.x;
    __shared__ float rv[256];
    float lm = -FLT_MAX;
    for (int j = t; j < N; j += 256) lm = fmaxf(lm, rowmax[b * N + j]);
    rv[t] = lm;
    __syncthreads();
    for (int s = 128; s > 0; s >>= 1) {
        if (t < s) rv[t] = fmaxf(rv[t], rv[t + s]);
        __syncthreads();
    }
    if (t == 0) dmax[b] = rv[0];
}

// ---------------------------------------------------------------------------
// K3: dist_peak = min over j with dens[j] > dens[i] of d[i,j] (else dmax);
// score = fp32(dist_peak * density) emulated exactly; packed rank key.
__global__ __launch_bounds__(256) void k_score(const float* __restrict__ y,
                                               const float* __restrict__ rel,
                                               const float* __restrict__ ynorm,
                                               const uint32_t* __restrict__ densbits,
                                               const float* __restrict__ dmax,
                                               unsigned long long* __restrict__ keys) {
    const int i = blockIdx.x;
    const int b = blockIdx.y;
    const int t = threadIdx.x;

    const uint32_t bi = densbits[b * N + i];
    if (bi == 0u) {
        if (t == 0) keys[b * N + i] =
            (unsigned long long)(0xFFFFFFFFu - (uint32_t)i);
        return;
    }

    __shared__ float yi[C];
    __shared__ float rv[256];

    const float* yb = y + (size_t)b * C * N;
    if (t < C) yi[t] = yb[(size_t)t * N + i];
    __syncthreads();

    const float ni = ynorm[b * N + i];
    float mn = FLT_MAX;
    for (int j = t; j < N; j += 256) {
        if (densbits[b * N + j] > bi) {
            const float* p = yb + j;
            float dot = 0.f;
            #pragma unroll 8
            for (int c = 0; c < C; ++c) dot += yi[c] * p[(size_t)c * N];
            float d = ni + ynorm[b * N + j] - 2.f * dot + rel[(size_t)i * N + j];
            mn = fminf(mn, d);
        }
    }
    rv[t] = mn;
    __syncthreads();
    for (int s = 128; s > 0; s >>= 1) {
        if (t < s) rv[t] = fminf(rv[t], rv[t + s]);
        __syncthreads();
    }
    if (t == 0) {
        float dp = fminf(rv[0], dmax[b]);
        double p = (double)dp * (double)__uint_as_float(bi);
        float sf = (float)p;
        uint32_t sb = (sf < 0x1p-126f) ? 0u : __float_as_uint(sf);
        keys[b * N + i] = ((unsigned long long)sb << 32)
                        | (unsigned long long)(0xFFFFFFFFu - (uint32_t)i);
    }
}

// ---------------------------------------------------------------------------
// K4: per-batch bitonic sort of packed keys, descending -> top M indices.
// 1024 threads (was 512) — halves sequential steps; only 8 blocks exist.
__global__ __launch_bounds__(1024) void k_topm(const unsigned long long* __restrict__ keys,
                                               int* __restrict__ sidx) {
    constexpr int SZ = 4096;
    int b = blockIdx.x, t = threadIdx.x;
    __shared__ unsigned long long ks[SZ];
    for (int i = t; i < SZ; i += 1024) ks[i] = (i < N) ? keys[b * N + i] : 0ull;
    __syncthreads();
    for (int k = 2; k <= SZ; k <<= 1) {
        for (int j = k >> 1; j > 0; j >>= 1) {
            for (int i = t; i < SZ; i += 1024) {
                int ixj = i ^ j;
                if (ixj > i) {
                    bool up = ((i & k) == 0);
                    unsigned long long a = ks[i], c2 = ks[ixj];
                    bool doSwap = up ? (a < c2) : (a > c2);  // descending
                    if (doSwap) { ks[i] = c2; ks[ixj] = a; }
                }
            }
            __syncthreads();
        }
    }
    for (int m = t; m < M; m += 1024)
        sidx[b * M + m] = (int)(0xFFFFFFFFu - (uint32_t)(ks[m] & 0xFFFFFFFFull));
}

// ---------------------------------------------------------------------------
// K5 v2: gather centers TRANSPOSED: cenT[b][c][m] = y[b][c][sidx[m]].
__global__ __launch_bounds__(256) void k_cen(const float* __restrict__ y,
                                             const int* __restrict__ sidx,
                                             const float* __restrict__ ynorm,
                                             float* __restrict__ cenT,
                                             float* __restrict__ cnorm) {
    const int b = blockIdx.y;
    const int m = blockIdx.x * 256 + threadIdx.x;
    if (m >= M) return;
    const int j = sidx[b * M + m];
    cnorm[b * M + m] = ynorm[b * N + j];
    const float* yb = y + (size_t)b * C * N;
    float* ct = cenT + (size_t)b * C * M;
    #pragma unroll 8
    for (int c = 0; c < C; ++c)
        ct[(size_t)c * M + m] = yb[(size_t)c * N + j];
}

// ---------------------------------------------------------------------------
// K6 v3 (xT path): GEMM A-fragments from xT wave-uniform; no LDS staging.
// Softmax / top-5 identical to validated v2.
__global__ __launch_bounds__(256) void k_assign_t(const float* __restrict__ xT,
                                                  const float* __restrict__ cenT,
                                                  const float* __restrict__ xnorm,
                                                  const float* __restrict__ cnorm,
                                                  float* __restrict__ assign,
                                                  int* __restrict__ nnidx) {
    const int b  = blockIdx.y;
    const int i0 = blockIdx.x * 8;
    const int t  = threadIdx.x;

    __shared__ __align__(16) float Ss[8][788];
    __shared__ float xnS[8];

    const float* xTb = xT + (size_t)b * N * C;
    const float* ct  = cenT + (size_t)b * C * M;

    if (t < 8) xnS[t] = xnorm[b * N + i0 + t];
    __syncthreads();

    if (t < 196) {
        const int mt = 4 * t;
        float acc[8][4];
        #pragma unroll
        for (int r = 0; r < 8; ++r)
            #pragma unroll
            for (int q = 0; q < 4; ++q) acc[r][q] = 0.f;

        for (int c0 = 0; c0 < C; c0 += 4) {
            float4 bq0 = *reinterpret_cast<const float4*>(ct + (size_t)(c0 + 0) * M + mt);
            float4 bq1 = *reinterpret_cast<const float4*>(ct + (size_t)(c0 + 1) * M + mt);
            float4 bq2 = *reinterpret_cast<const float4*>(ct + (size_t)(c0 + 2) * M + mt);
            float4 bq3 = *reinterpret_cast<const float4*>(ct + (size_t)(c0 + 3) * M + mt);
            #pragma unroll
            for (int r = 0; r < 8; ++r) {
                float4 a4 = *reinterpret_cast<const float4*>(
                    xTb + (size_t)(i0 + r) * C + c0);   // wave-uniform addr
                acc[r][0] += a4.x * bq0.x; acc[r][1] += a4.x * bq0.y;
                acc[r][2] += a4.x * bq0.z; acc[r][3] += a4.x * bq0.w;
                acc[r][0] += a4.y * bq1.x; acc[r][1] += a4.y * bq1.y;
                acc[r][2] += a4.y * bq1.z; acc[r][3] += a4.y * bq1.w;
                acc[r][0] += a4.z * bq2.x; acc[r][1] += a4.z * bq2.y;
                acc[r][2] += a4.z * bq2.z; acc[r][3] += a4.z * bq2.w;
                acc[r][0] += a4.w * bq3.x; acc[r][1] += a4.w * bq3.y;
                acc[r][2] += a4.w * bq3.z; acc[r][3] += a4.w * bq3.w;
            }
        }

        float4 cn4 = *reinterpret_cast<const float4*>(cnorm + (size_t)b * M + mt);
        float cn[4] = {cn4.x, cn4.y, cn4.z, cn4.w};
        #pragma unroll
        for (int r = 0; r < 8; ++r) {
            float xn = xnS[r];
            float sv[4];
            #pragma unroll
            for (int q = 0; q < 4; ++q)
                sv[q] = -(xn + cn[q] - 2.f * acc[r][q]);
            *reinterpret_cast<float4*>(&Ss[r][mt]) =
                make_float4(sv[0], sv[1], sv[2], sv[3]);
        }
    }
    __syncthreads();

    const int r = t >> 5;
    const int l = t & 31;

    float lm = -FLT_MAX;
    for (int m = l; m < M; m += 32) lm = fmaxf(lm, Ss[r][m]);
    #pragma unroll
    for (int off = 16; off > 0; off >>= 1)
        lm = fmaxf(lm, __shfl_xor(lm, off, 32));
    const float smax = lm;

    float ls = 0.f;
    for (int m = l; m < M; m += 32) ls += expf(Ss[r][m] - smax);
    #pragma unroll
    for (int off = 16; off > 0; off >>= 1)
        ls += __shfl_xor(ls, off, 32);
    const float inv = 1.f / ls;

    float* arow = assign + ((size_t)b * N + i0 + r) * M;
    for (int m = l; m < M; m += 32) arow[m] = expf(Ss[r][m] - smax) * inv;

    for (int round = 0; round < TK; ++round) {
        float lv = -FLT_MAX; int li = M;
        for (int m = l; m < M; m += 32) {
            float v = Ss[r][m];
            if (v > lv) { lv = v; li = m; }
        }
        #pragma unroll
        for (int off = 16; off > 0; off >>= 1) {
            float ov = __shfl_xor(lv, off, 32);
            int   oi = __shfl_xor(li, off, 32);
            if (ov > lv || (ov == lv && oi < li)) { lv = ov; li = oi; }
        }
        if (l == 0) {
            nnidx[((size_t)b * N + i0 + r) * TK + round] = li;
            Ss[r][li] = -FLT_MAX;
        }
        __syncthreads();
    }
}

// ---------------------------------------------------------------------------
// K6 v2 (fallback, validated round 8)
__global__ __launch_bounds__(256) void k_assign(const float* __restrict__ x,
                                                const float* __restrict__ cenT,
                                                const float* __restrict__ xnorm,
                                                const float* __restrict__ cnorm,
                                                float* __restrict__ assign,
                                                int* __restrict__ nnidx) {
    const int b  = blockIdx.y;
    const int i0 = blockIdx.x * 8;
    const int t  = threadIdx.x;

    __shared__ __align__(16) float xiS[8][100];
    __shared__ __align__(16) float Ss[8][788];
    __shared__ float xnS[8];

    const float* xb = x + (size_t)b * C * N;
    const float* ct = cenT + (size_t)b * C * M;

    for (int e = t; e < C * 2; e += 256) {
        int c = e >> 1, n4 = (e & 1) << 2;
        float4 v = *reinterpret_cast<const float4*>(xb + (size_t)c * N + i0 + n4);
        xiS[n4 + 0][c] = v.x;
        xiS[n4 + 1][c] = v.y;
        xiS[n4 + 2][c] = v.z;
        xiS[n4 + 3][c] = v.w;
    }
    if (t < 8) xnS[t] = xnorm[b * N + i0 + t];
    __syncthreads();

    if (t < 196) {
        const int mt = 4 * t;
        float acc[8][4];
        #pragma unroll
        for (int r = 0; r < 8; ++r)
            #pragma unroll
            for (int q = 0; q < 4; ++q) acc[r][q] = 0.f;

        for (int c0 = 0; c0 < C; c0 += 4) {
            float4 bq0 = *reinterpret_cast<const float4*>(ct + (size_t)(c0 + 0) * M + mt);
            float4 bq1 = *reinterpret_cast<const float4*>(ct + (size_t)(c0 + 1) * M + mt);
            float4 bq2 = *reinterpret_cast<const float4*>(ct + (size_t)(c0 + 2) * M + mt);
            float4 bq3 = *reinterpret_cast<const float4*>(ct + (size_t)(c0 + 3) * M + mt);
            #pragma unroll
            for (int r = 0; r < 8; ++r) {
                float4 a4 = *reinterpret_cast<const float4*>(&xiS[r][c0]);
                acc[r][0] += a4.x * bq0.x; acc[r][1] += a4.x * bq0.y;
                acc[r][2] += a4.x * bq0.z; acc[r][3] += a4.x * bq0.w;
                acc[r][0] += a4.y * bq1.x; acc[r][1] += a4.y * bq1.y;
                acc[r][2] += a4.y * bq1.z; acc[r][3] += a4.y * bq1.w;
                acc[r][0] += a4.z * bq2.x; acc[r][1] += a4.z * bq2.y;
                acc[r][2] += a4.z * bq2.z; acc[r][3] += a4.z * bq2.w;
                acc[r][0] += a4.w * bq3.x; acc[r][1] += a4.w * bq3.y;
                acc[r][2] += a4.w * bq3.z; acc[r][3] += a4.w * bq3.w;
            }
        }

        float4 cn4 = *reinterpret_cast<const float4*>(cnorm + (size_t)b * M + mt);
        float cn[4] = {cn4.x, cn4.y, cn4.z, cn4.w};
        #pragma unroll
        for (int r = 0; r < 8; ++r) {
            float xn = xnS[r];
            float sv[4];
            #pragma unroll
            for (int q = 0; q < 4; ++q)
                sv[q] = -(xn + cn[q] - 2.f * acc[r][q]);
            *reinterpret_cast<float4*>(&Ss[r][mt]) =
                make_float4(sv[0], sv[1], sv[2], sv[3]);
        }
    }
    __syncthreads();

    const int r = t >> 5;
    const int l = t & 31;

    float lm = -FLT_MAX;
    for (int m = l; m < M; m += 32) lm = fmaxf(lm, Ss[r][m]);
    #pragma unroll
    for (int off = 16; off > 0; off >>= 1)
        lm = fmaxf(lm, __shfl_xor(lm, off, 32));
    const float smax = lm;

    float ls = 0.f;
    for (int m = l; m < M; m += 32) ls += expf(Ss[r][m] - smax);
    #pragma unroll
    for (int off = 16; off > 0; off >>= 1)
        ls += __shfl_xor(ls, off, 32);
    const float inv = 1.f / ls;

    float* arow = assign + ((size_t)b * N + i0 + r) * M;
    for (int m = l; m < M; m += 32) arow[m] = expf(Ss[r][m] - smax) * inv;

    for (int round = 0; round < TK; ++round) {
        float lv = -FLT_MAX; int li = M;
        for (int m = l; m < M; m += 32) {
            float v = Ss[r][m];
            if (v > lv) { lv = v; li = m; }
        }
        #pragma unroll
        for (int off = 16; off > 0; off >>= 1) {
            float ov = __shfl_xor(lv, off, 32);
            int   oi = __shfl_xor(li, off, 32);
            if (ov > lv || (ov == lv && oi < li)) { lv = ov; li = oi; }
        }
        if (l == 0) {
            nnidx[((size_t)b * N + i0 + r) * TK + round] = li;
            Ss[r][li] = -FLT_MAX;
        }
        __syncthreads();
    }
}

// ---------------------------------------------------------------------------
// K7: agg[b,m,c] = (sum_n assign[n,m] * x[c,n]) / (mass_m + 1e-6)
__global__ __launch_bounds__(256) void k_agg(const float* __restrict__ assign,
                                             const float* __restrict__ x,
                                             float* __restrict__ aggws) {
    const int b = blockIdx.y;
    const int m0 = blockIdx.x * 16;
    const int t = threadIdx.x;
    __shared__ float As[64][16];
    __shared__ float Xs[96][65];
    __shared__ float minv[16];

    float acc[6] = {0.f, 0.f, 0.f, 0.f, 0.f, 0.f};
    float massacc = 0.f;

    for (int n0 = 0; n0 < N; n0 += 64) {
        for (int e = t; e < 64 * 16; e += 256) {
            int nn = e >> 4, mm = e & 15;
            As[nn][mm] = assign[((size_t)b * N + n0 + nn) * M + m0 + mm];
        }
        for (int e = t; e < 96 * 64; e += 256) {
            int c = e >> 6, nn = e & 63;
            Xs[c][nn] = x[((size_t)b * C + c) * N + n0 + nn];
        }
        __syncthreads();
        if (t < 16) {
            #pragma unroll
            for (int nn = 0; nn < 64; ++nn) massacc += As[nn][t];
        }
        #pragma unroll
        for (int u = 0; u < 6; ++u) {
            int e = t + u * 256;
            int mm = e & 15, c = e >> 4;
            float a = acc[u];
            #pragma unroll 8
            for (int nn = 0; nn < 64; ++nn) a += As[nn][mm] * Xs[c][nn];
            acc[u] = a;
        }
        __syncthreads();
    }
    if (t < 16) minv[t] = 1.f / (massacc + 1e-6f);
    __syncthreads();
    #pragma unroll
    for (int u = 0; u < 6; ++u) {
        int e = t + u * 256;
        int mm = e & 15, c = e >> 4;
        aggws[((size_t)b * M + m0 + mm) * C + c] = acc[u] * minv[mm];
    }
}

// ---------------------------------------------------------------------------
// K8: per-center FFN with residual; writes updated agg (ws) and `refined`
__global__ __launch_bounds__(128) void k_ffn(const float* __restrict__ w1,
                                             const float* __restrict__ b1,
                                             const float* __restrict__ g1,
                                             const float* __restrict__ bt1,
                                             const float* __restrict__ w2,
                                             const float* __restrict__ b2,
                                             const float* __restrict__ g2,
                                             const float* __restrict__ bt2,
                                             float* __restrict__ aggws,
                                             float* __restrict__ refined) {
    const int m = blockIdx.x;
    const int b = blockIdx.y;
    const int t = threadIdx.x;
    __shared__ float ar[C];
    __shared__ float hd[C4];

    if (t < C) ar[t] = aggws[((size_t)b * M + m) * C + t];
    __syncthreads();

    for (int o = t; o < C4; o += 128) {
        const float* w = w1 + (size_t)o * C;
        float h = b1[o];
        #pragma unroll 8
        for (int c = 0; c < C; ++c) h += w[c] * ar[c];
        h = h * g1[o] + bt1[o];
        hd[o] = fmaxf(h, 0.f);
    }
    __syncthreads();

    if (t < C) {
        const float* w = w2 + (size_t)t * C4;
        float f = b2[t];
        #pragma unroll 8
        for (int o = 0; o < C4; ++o) f += w[o] * hd[o];
        float v = ar[t] + (f * g2[t] + bt2[t]);
        aggws[((size_t)b * M + m) * C + t] = v;
        refined[((size_t)b * C + t) * M + m] = v;
    }
}

// ---------------------------------------------------------------------------
// K9: rel = max over top-5 agg rows - xf; interleaved xcat;
// out = relu((nn_w @ xcat + nn_b) * g + bt), stored (B, OUT, N)
__global__ __launch_bounds__(256) void k_final(const float* __restrict__ x,
                                               const float* __restrict__ aggws,
                                               const int* __restrict__ nnidx,
                                               const float* __restrict__ nnw,
                                               const float* __restrict__ nnb,
                                               const float* __restrict__ nng,
                                               const float* __restrict__ nnbt,
                                               float* __restrict__ out) {
    const int b = blockIdx.y;
    const int n0 = blockIdx.x * 16;
    const int t = threadIdx.x;
    __shared__ float xc[16][193];
    __shared__ int nid[16 * TK];

    if (t < 16 * TK) nid[t] = nnidx[((size_t)b * N + n0) * TK + t];
    __syncthreads();

    for (int e = t; e < C * 16; e += 256) {
        int c = e >> 4, r = e & 15;
        float xv = x[((size_t)b * C + c) * N + n0 + r];
        float mx = -FLT_MAX;
        #pragma unroll
        for (int k = 0; k < TK; ++k) {
            int j = nid[r * TK + k];
            mx = fmaxf(mx, aggws[((size_t)b * M + j) * C + c]);
        }
        xc[r][2 * c]     = xv;
        xc[r][2 * c + 1] = mx - xv;
    }
    __syncthreads();

    const int r = t & 15;
    const int og = t >> 4;
    #pragma unroll
    for (int oo = 0; oo < 12; ++oo) {
        int o = og + (oo << 4);
        const float* w = nnw + (size_t)o * (2 * C);
        float a = nnb[o];
        #pragma unroll 8
        for (int cc = 0; cc < 2 * C; ++cc) a += w[cc] * xc[r][cc];
        a = a * nng[o] + nnbt[o];
        out[((size_t)b * OUT + o) * N + n0 + r] = fmaxf(a, 0.f);
    }
}

// ---------------------------------------------------------------------------
extern "C" void kernel_launch(void* const* d_in, const int* in_sizes, int n_in,
                              void* d_out, int out_size, void* d_ws, size_t ws_size,
                              hipStream_t stream) {
    const float* x    = (const float*)d_in[0];
    const float* rel  = (const float*)d_in[1];
    const float* y    = (const float*)d_in[2];
    const float* w1   = (const float*)d_in[3];
    const float* b1   = (const float*)d_in[4];
    const float* g1   = (const float*)d_in[5];
    const float* bt1  = (const float*)d_in[6];
    const float* w2   = (const float*)d_in[7];
    const float* b2   = (const float*)d_in[8];
    const float* g2   = (const float*)d_in[9];
    const float* bt2  = (const float*)d_in[10];
    const float* nnw  = (const float*)d_in[11];
    const float* nnb  = (const float*)d_in[12];
    const float* nng  = (const float*)d_in[13];
    const float* nnbt = (const float*)d_in[14];

    float* out     = (float*)d_out;
    float* refined = out + (size_t)B * OUT * N;

    char* w = (char*)d_ws;
    auto alloc = [&](size_t nbytes) -> void* {
        void* p = (void*)w;
        w += (nbytes + 255) & ~(size_t)255;
        return p;
    };
    float*    ynorm    = (float*)   alloc((size_t)B * N * 4);
    float*    xnorm    = (float*)   alloc((size_t)B * N * 4);
    uint32_t* densbits = (uint32_t*)alloc((size_t)B * N * 4);
    float*    rowmax   = (float*)   alloc((size_t)B * N * 4);
    float*    dmaxv    = (float*)   alloc((size_t)B * 4);
    unsigned long long* keys = (unsigned long long*)alloc((size_t)B * N * 8);
    int*      sidx     = (int*)     alloc((size_t)B * M * 4);
    float*    cnorm    = (float*)   alloc((size_t)B * M * 4);
    float*    cenT     = (float*)   alloc((size_t)B * C * M * 4);
    float*    aggws    = (float*)   alloc((size_t)B * M * C * 4);
    int*      nnidx    = (int*)     alloc((size_t)B * N * TK * 4);
    float*    assign   = (float*)   alloc((size_t)B * N * M * 4);

    // optional transposed copies (gated on workspace size)
    size_t used = (size_t)(w - (char*)d_ws);
    size_t tbytes = (size_t)B * N * C * 4;
    float* yT = nullptr;
    float* xT = nullptr;
    if (ws_size >= used + 2 * (tbytes + 256)) {
        yT = (float*)alloc(tbytes);
        xT = (float*)alloc(tbytes);
    }

    if (yT) k_tr<<<dim3(N / 32, C / 32, B), dim3(256), 0, stream>>>(y, x, yT, xT);

    k_norms<<<dim3((B * N + 255) / 256), dim3(256), 0, stream>>>(y, x, ynorm, xnorm);

    if (yT)
        k_density_t<<<dim3(N / DR, B), dim3(256), 0, stream>>>(y, yT, rel, ynorm, densbits, rowmax);
    else
        k_density<<<dim3(N / DR, B), dim3(256), 0, stream>>>(y, rel, ynorm, densbits, rowmax);

    k_dmax<<<dim3(B), dim3(256), 0, stream>>>(rowmax, dmaxv);
    k_score<<<dim3(N, B), dim3(256), 0, stream>>>(y, rel, ynorm, densbits, dmaxv, keys);
    k_topm<<<dim3(B), dim3(1024), 0, stream>>>(keys, sidx);
    k_cen<<<dim3((M + 255) / 256, B), dim3(256), 0, stream>>>(y, sidx, ynorm, cenT, cnorm);

    if (xT)
        k_assign_t<<<dim3(N / 8, B), dim3(256), 0, stream>>>(xT, cenT, xnorm, cnorm, assign, nnidx);
    else
        k_assign<<<dim3(N / 8, B), dim3(256), 0, stream>>>(x, cenT, xnorm, cnorm, assign, nnidx);

    k_agg<<<dim3(M / 16, B), dim3(256), 0, stream>>>(assign, x, aggws);
    k_ffn<<<dim3(M, B), dim3(128), 0, stream>>>(w1, b1, g1, bt1, w2, b2, g2, bt2, aggws, refined);
    k_final<<<dim3(N / 16, B), dim3(256), 0, stream>>>(x, aggws, nnidx, nnw, nnb, nng, nnbt, out);
}

// Round 12
// 1282.200 us; speedup vs baseline: 1.6201x; 1.1291x over previous
//
#include <hip/hip_runtime.h>
#include <float.h>
#include <math.h>
#include <stdint.h>

// Problem constants (match reference)
constexpr int B   = 8;
constexpr int C   = 96;
constexpr int N   = 3136;   // 56*56
constexpr int M   = 784;    // RATIO*N
constexpr int C4  = 384;    // 4*C
constexpr int OUT = 192;
constexpr int KD  = 16;     // K_DPC
constexpr int TK  = 5;      // TOPK
constexpr int NSPLIT = 7;   // k_agg split-N factor (N/7 = 448 = 7*64)

// ---------------------------------------------------------------------------
// fp32 round-to-nearest of a positive double WITH flush-to-zero of subnormal
// results (validated semantics for the reference's exp underflow).
__device__ inline uint32_t f32q_ftz(double t) {
    if (t <= 0.0) return 0u;
    float f = (float)t;              // exact RN cvt (double->float)
    if (f < 0x1p-126f) return 0u;    // subnormal result -> flush to zero
    return __float_as_uint(f);
}

// ---------------------------------------------------------------------------
// K0: per-point squared norms of y and x (both laid out (B,C,N))
__global__ __launch_bounds__(256) void k_norms(const float* __restrict__ y,
                                               const float* __restrict__ x,
                                               float* __restrict__ ynorm,
                                               float* __restrict__ xnorm) {
    int id = blockIdx.x * 256 + threadIdx.x;
    if (id >= B * N) return;
    int b = id / N, n = id % N;
    const float* yb = y + (size_t)b * C * N + n;
    const float* xb = x + (size_t)b * C * N + n;
    float sy = 0.f, sx = 0.f;
    #pragma unroll 8
    for (int c = 0; c < C; ++c) {
        float a = yb[(size_t)c * N]; sy += a * a;
        float d = xb[(size_t)c * N]; sx += d * d;
    }
    ynorm[id] = sy;
    xnorm[id] = sx;
}

// ---------------------------------------------------------------------------
// K-TR: tiled transpose of y and x into [b][n][c] layout (for wave-uniform
// A-panel reads). 32x32 tiles, padded LDS.
__global__ __launch_bounds__(256) void k_tr(const float* __restrict__ y,
                                            const float* __restrict__ x,
                                            float* __restrict__ yT,
                                            float* __restrict__ xT) {
    __shared__ float ty[32][33];
    __shared__ float tx[32][33];
    const int b  = blockIdx.z;
    const int n0 = blockIdx.x * 32;
    const int c0 = blockIdx.y * 32;
    const int tn = threadIdx.x & 31;
    const int tc = threadIdx.x >> 5;   // 0..7
    #pragma unroll
    for (int k = 0; k < 4; ++k) {
        int c = c0 + tc + 8 * k;
        ty[tc + 8 * k][tn] = y[((size_t)b * C + c) * N + n0 + tn];
        tx[tc + 8 * k][tn] = x[((size_t)b * C + c) * N + n0 + tn];
    }
    __syncthreads();
    #pragma unroll
    for (int k = 0; k < 4; ++k) {
        int n = n0 + tc + 8 * k;
        yT[((size_t)b * N + n) * C + c0 + tn] = ty[tn][tc + 8 * k];
        xT[((size_t)b * N + n) * C + c0 + tn] = tx[tn][tc + 8 * k];
    }
}

constexpr int DR = 8;       // rows per block
constexpr int DCOLS = 1024; // cols per tile

// ---------------------------------------------------------------------------
// K1 v7 (yT path, validated round 11)
__global__ __launch_bounds__(256) void k_density_t(const float* __restrict__ y,
                                                   const float* __restrict__ yT,
                                                   const float* __restrict__ rel,
                                                   const float* __restrict__ ynorm,
                                                   uint32_t* __restrict__ densbits,
                                                   float* __restrict__ rowmax) {
    const int b  = blockIdx.y;
    const int i0 = blockIdx.x * DR;
    const int t  = threadIdx.x;
    const int gr = t >> 5;      // row group 0..7
    const int gl = t & 31;      // lane in group

    __shared__ float niS[DR];
    __shared__ float s16[DR][17];
    __shared__ float thrS[DR];
    __shared__ float minb[DR][257];
    __shared__ float candV[DR][193];
    __shared__ int   candC[DR];

    const float* yb  = y  + (size_t)b * C * N;
    const float* yTb = yT + (size_t)b * N * C;

    if (t < DR) {
        niS[t] = ynorm[b * N + i0 + t];
        thrS[t] = FLT_MAX;
        candC[t] = 0;
        #pragma unroll
        for (int q = 0; q < 16; ++q) s16[t][q] = FLT_MAX;
    }
    float rm[DR];
    #pragma unroll
    for (int r = 0; r < DR; ++r) rm[r] = -FLT_MAX;
    __syncthreads();

    for (int tile = 0; tile < 4; ++tile) {
        const int jt = tile * DCOLS + 4 * t;
        const bool active = (jt < N);

        float dv[DR][4];

        if (active) {
            float acc[DR][4];
            #pragma unroll
            for (int r = 0; r < DR; ++r)
                #pragma unroll
                for (int q = 0; q < 4; ++q) acc[r][q] = 0.f;

            for (int c0 = 0; c0 < C; c0 += 4) {
                float4 bq0 = *reinterpret_cast<const float4*>(yb + (size_t)(c0 + 0) * N + jt);
                float4 bq1 = *reinterpret_cast<const float4*>(yb + (size_t)(c0 + 1) * N + jt);
                float4 bq2 = *reinterpret_cast<const float4*>(yb + (size_t)(c0 + 2) * N + jt);
                float4 bq3 = *reinterpret_cast<const float4*>(yb + (size_t)(c0 + 3) * N + jt);
                #pragma unroll
                for (int r = 0; r < DR; ++r) {
                    float4 a4 = *reinterpret_cast<const float4*>(
                        yTb + (size_t)(i0 + r) * C + c0);   // wave-uniform addr
                    acc[r][0] += a4.x * bq0.x; acc[r][1] += a4.x * bq0.y;
                    acc[r][2] += a4.x * bq0.z; acc[r][3] += a4.x * bq0.w;
                    acc[r][0] += a4.y * bq1.x; acc[r][1] += a4.y * bq1.y;
                    acc[r][2] += a4.y * bq1.z; acc[r][3] += a4.y * bq1.w;
                    acc[r][0] += a4.z * bq2.x; acc[r][1] += a4.z * bq2.y;
                    acc[r][2] += a4.z * bq2.z; acc[r][3] += a4.z * bq2.w;
                    acc[r][0] += a4.w * bq3.x; acc[r][1] += a4.w * bq3.y;
                    acc[r][2] += a4.w * bq3.z; acc[r][3] += a4.w * bq3.w;
                }
            }

            float4 yn4 = *reinterpret_cast<const float4*>(ynorm + (size_t)b * N + jt);
            float yn[4] = {yn4.x, yn4.y, yn4.z, yn4.w};
            #pragma unroll
            for (int r = 0; r < DR; ++r) {
                float4 rl4 = *reinterpret_cast<const float4*>(rel + (size_t)(i0 + r) * N + jt);
                float rl[4] = {rl4.x, rl4.y, rl4.z, rl4.w};
                float niv = niS[r];
                #pragma unroll
                for (int q = 0; q < 4; ++q)
                    dv[r][q] = niv + yn[q] - 2.f * acc[r][q] + rl[q];
                rm[r] = fmaxf(rm[r],
                        fmaxf(fmaxf(dv[r][0], dv[r][1]), fmaxf(dv[r][2], dv[r][3])));
            }
        }

        if (tile == 0) {
            #pragma unroll
            for (int r = 0; r < DR; ++r) {
                float mn = active
                    ? fminf(fminf(dv[r][0], dv[r][1]), fminf(dv[r][2], dv[r][3]))
                    : FLT_MAX;
                minb[r][t] = mn;
            }
            __syncthreads();
            {
                float t16 = FLT_MAX;
                for (int round = 0; round < 16; ++round) {
                    float lv = FLT_MAX; int li = 0x7fffffff;
                    #pragma unroll
                    for (int e = 0; e < 8; ++e) {
                        int idx = gl * 8 + e;
                        float v = minb[gr][idx];
                        if (v < lv) { lv = v; li = idx; }
                    }
                    #pragma unroll
                    for (int off = 16; off > 0; off >>= 1) {
                        float ov = __shfl_xor(lv, off, 32);
                        int   oi = __shfl_xor(li, off, 32);
                        if (ov < lv || (ov == lv && oi < li)) { lv = ov; li = oi; }
                    }
                    if ((li >> 3) == gl) minb[gr][li] = FLT_MAX;
                    t16 = lv;
                }
                if (gl == 0) thrS[gr] = t16;
            }
            __syncthreads();
        }

        if (active) {
            #pragma unroll
            for (int r = 0; r < DR; ++r) {
                float thr = thrS[r];
                #pragma unroll
                for (int q = 0; q < 4; ++q) {
                    float v = dv[r][q];
                    bool take = (tile == 0) ? (v <= thr) : (v < thr);
                    if (take) {
                        int p = atomicAdd(&candC[r], 1);
                        if (p < 192) candV[r][p] = v;
                    }
                }
            }
        }
        __syncthreads();

        if (t < DR) {
            int cnt = candC[t];
            if (cnt > 192) cnt = 192;
            for (int qq = 0; qq < cnt; ++qq) {
                float v = candV[t][qq];
                if (v < s16[t][15]) {
                    int pos = 15;
                    while (pos > 0 && s16[t][pos - 1] > v) {
                        s16[t][pos] = s16[t][pos - 1];
                        --pos;
                    }
                    s16[t][pos] = v;
                }
            }
            candC[t] = 0;
            thrS[t] = s16[t][15];
        }
        __syncthreads();
    }

    #pragma unroll
    for (int r = 0; r < DR; ++r) minb[r][t] = rm[r];
    __syncthreads();
    {
        float mx = -FLT_MAX;
        #pragma unroll
        for (int e = 0; e < 8; ++e) mx = fmaxf(mx, minb[gr][gl * 8 + e]);
        #pragma unroll
        for (int off = 16; off > 0; off >>= 1)
            mx = fmaxf(mx, __shfl_xor(mx, off, 32));
        if (gl == 0) {
            rowmax[b * N + i0 + gr] = mx;
            float r8[8];
            #pragma unroll
            for (int j2 = 0; j2 < 8; ++j2) r8[j2] = s16[gr][j2] + s16[gr][8 + j2];
            float s = ((r8[0] + r8[1]) + (r8[2] + r8[3]))
                    + ((r8[4] + r8[5]) + (r8[6] + r8[7]));
            float mean = s * (1.0f / 16.0f);
            densbits[b * N + i0 + gr] = f32q_ftz(exp(-(double)mean));
        }
    }
}

// ---------------------------------------------------------------------------
// K1 v6 (fallback, validated round 10)
__global__ __launch_bounds__(256) void k_density(const float* __restrict__ y,
                                                 const float* __restrict__ rel,
                                                 const float* __restrict__ ynorm,
                                                 uint32_t* __restrict__ densbits,
                                                 float* __restrict__ rowmax) {
    const int b  = blockIdx.y;
    const int i0 = blockIdx.x * DR;
    const int t  = threadIdx.x;

    __shared__ __align__(16) float yiS[DR][100];
    __shared__ float niS[DR];
    __shared__ float s16[DR][17];
    __shared__ float thrS[DR];
    __shared__ float minb[DR][257];
    __shared__ float candV[DR][193];
    __shared__ int   candC[DR];

    const float* yb = y + (size_t)b * C * N;

    for (int e = t; e < C * 2; e += 256) {
        int c = e >> 1, n4 = (e & 1) << 2;
        float4 v = *reinterpret_cast<const float4*>(yb + (size_t)c * N + i0 + n4);
        yiS[n4 + 0][c] = v.x;
        yiS[n4 + 1][c] = v.y;
        yiS[n4 + 2][c] = v.z;
        yiS[n4 + 3][c] = v.w;
    }
    if (t < DR) {
        niS[t] = ynorm[b * N + i0 + t];
        thrS[t] = FLT_MAX;
        candC[t] = 0;
        #pragma unroll
        for (int q = 0; q < 16; ++q) s16[t][q] = FLT_MAX;
    }
    float rm[DR];
    #pragma unroll
    for (int r = 0; r < DR; ++r) rm[r] = -FLT_MAX;
    __syncthreads();

    for (int tile = 0; tile < 4; ++tile) {
        const int jt = tile * DCOLS + 4 * t;
        const bool active = (jt < N);

        float acc[DR][4];
        #pragma unroll
        for (int r = 0; r < DR; ++r)
            #pragma unroll
            for (int q = 0; q < 4; ++q) acc[r][q] = 0.f;

        float dv[DR][4];

        if (active) {
            for (int c0 = 0; c0 < C; c0 += 4) {
                float4 bq0 = *reinterpret_cast<const float4*>(yb + (size_t)(c0 + 0) * N + jt);
                float4 bq1 = *reinterpret_cast<const float4*>(yb + (size_t)(c0 + 1) * N + jt);
                float4 bq2 = *reinterpret_cast<const float4*>(yb + (size_t)(c0 + 2) * N + jt);
                float4 bq3 = *reinterpret_cast<const float4*>(yb + (size_t)(c0 + 3) * N + jt);
                #pragma unroll
                for (int r = 0; r < DR; ++r) {
                    float4 a4 = *reinterpret_cast<const float4*>(&yiS[r][c0]);
                    acc[r][0] += a4.x * bq0.x; acc[r][1] += a4.x * bq0.y;
                    acc[r][2] += a4.x * bq0.z; acc[r][3] += a4.x * bq0.w;
                    acc[r][0] += a4.y * bq1.x; acc[r][1] += a4.y * bq1.y;
                    acc[r][2] += a4.y * bq1.z; acc[r][3] += a4.y * bq1.w;
                    acc[r][0] += a4.z * bq2.x; acc[r][1] += a4.z * bq2.y;
                    acc[r][2] += a4.z * bq2.z; acc[r][3] += a4.z * bq2.w;
                    acc[r][0] += a4.w * bq3.x; acc[r][1] += a4.w * bq3.y;
                    acc[r][2] += a4.w * bq3.z; acc[r][3] += a4.w * bq3.w;
                }
            }

            float4 yn4 = *reinterpret_cast<const float4*>(ynorm + (size_t)b * N + jt);
            float yn[4] = {yn4.x, yn4.y, yn4.z, yn4.w};
            #pragma unroll
            for (int r = 0; r < DR; ++r) {
                float4 rl4 = *reinterpret_cast<const float4*>(rel + (size_t)(i0 + r) * N + jt);
                float rl[4] = {rl4.x, rl4.y, rl4.z, rl4.w};
                float niv = niS[r];
                #pragma unroll
                for (int q = 0; q < 4; ++q)
                    dv[r][q] = niv + yn[q] - 2.f * acc[r][q] + rl[q];
                rm[r] = fmaxf(rm[r],
                        fmaxf(fmaxf(dv[r][0], dv[r][1]), fmaxf(dv[r][2], dv[r][3])));
            }
        }

        if (tile == 0) {
            #pragma unroll
            for (int r = 0; r < DR; ++r) {
                float mn = active
                    ? fminf(fminf(dv[r][0], dv[r][1]), fminf(dv[r][2], dv[r][3]))
                    : FLT_MAX;
                minb[r][t] = mn;
            }
            __syncthreads();
            if (t < DR) {
                #pragma unroll
                for (int q = 0; q < 16; ++q) candV[t][q] = FLT_MAX;
                for (int e = 0; e < 256; ++e) {
                    float v = minb[t][e];
                    if (v < candV[t][15]) {
                        int pos = 15;
                        while (pos > 0 && candV[t][pos - 1] > v) {
                            candV[t][pos] = candV[t][pos - 1];
                            --pos;
                        }
                        candV[t][pos] = v;
                    }
                }
                thrS[t] = candV[t][15];
            }
            __syncthreads();
        }

        if (active) {
            #pragma unroll
            for (int r = 0; r < DR; ++r) {
                float thr = thrS[r];
                #pragma unroll
                for (int q = 0; q < 4; ++q) {
                    float v = dv[r][q];
                    bool take = (tile == 0) ? (v <= thr) : (v < thr);
                    if (take) {
                        int p = atomicAdd(&candC[r], 1);
                        if (p < 192) candV[r][p] = v;
                    }
                }
            }
        }
        __syncthreads();

        if (t < DR) {
            int cnt = candC[t];
            if (cnt > 192) cnt = 192;
            for (int qq = 0; qq < cnt; ++qq) {
                float v = candV[t][qq];
                if (v < s16[t][15]) {
                    int pos = 15;
                    while (pos > 0 && s16[t][pos - 1] > v) {
                        s16[t][pos] = s16[t][pos - 1];
                        --pos;
                    }
                    s16[t][pos] = v;
                }
            }
            candC[t] = 0;
            thrS[t] = s16[t][15];
        }
        __syncthreads();
    }

    #pragma unroll
    for (int r = 0; r < DR; ++r) minb[r][t] = rm[r];
    __syncthreads();
    if (t < DR) {
        float mx = -FLT_MAX;
        for (int e = 0; e < 256; ++e) mx = fmaxf(mx, minb[t][e]);
        rowmax[b * N + i0 + t] = mx;

        float r8[8];
        #pragma unroll
        for (int j2 = 0; j2 < 8; ++j2) r8[j2] = s16[t][j2] + s16[t][8 + j2];
        float s = ((r8[0] + r8[1]) + (r8[2] + r8[3]))
                + ((r8[4] + r8[5]) + (r8[6] + r8[7]));
        float mean = s * (1.0f / 16.0f);
        densbits[b * N + i0 + t] = f32q_ftz(exp(-(double)mean));
    }
}

// ---------------------------------------------------------------------------
// K2: per-batch global max of d (fp32)
__global__ __launch_bounds__(256) void k_dmax(const float* __restrict__ rowmax,
                                              float* __restrict__ dmax) {
    int b = blockIdx.x, t = threadIdx.x;
    __shared__ float rv[256];
    float lm = -FLT_MAX;
    for (int j = t; j < N; j += 256) lm = fmaxf(lm, rowmax[b * N + j]);
    rv[t] = lm;
    __syncthreads();
    for (int s = 128; s > 0; s >>= 1) {
        if (t < s) rv[t] = fmaxf(rv[t], rv[t + s]);
        __syncthreads();
    }
    if (t == 0) dmax[b] = rv[0];
}

// ---------------------------------------------------------------------------
// K3: dist_peak = min over j with dens[j] > dens[i] of d[i,j] (else dmax);
// score = fp32(dist_peak * density) emulated exactly; packed rank key.
__global__ __launch_bounds__(256) void k_score(const float* __restrict__ y,
                                               const float* __restrict__ rel,
                                               const float* __restrict__ ynorm,
                                               const uint32_t* __restrict__ densbits,
                                               const float* __restrict__ dmax,
                                               unsigned long long* __restrict__ keys) {
    const int i = blockIdx.x;
    const int b = blockIdx.y;
    const int t = threadIdx.x;

    const uint32_t bi = densbits[b * N + i];
    if (bi == 0u) {
        if (t == 0) keys[b * N + i] =
            (unsigned long long)(0xFFFFFFFFu - (uint32_t)i);
        return;
    }

    __shared__ float yi[C];
    __shared__ float rv[256];

    const float* yb = y + (size_t)b * C * N;
    if (t < C) yi[t] = yb[(size_t)t * N + i];
    __syncthreads();

    const float ni = ynorm[b * N + i];
    float mn = FLT_MAX;
    for (int j = t; j < N; j += 256) {
        if (densbits[b * N + j] > bi) {
            const float* p = yb + j;
            float dot = 0.f;
            #pragma unroll 8
            for (int c = 0; c < C; ++c) dot += yi[c] * p[(size_t)c * N];
            float d = ni + ynorm[b * N + j] - 2.f * dot + rel[(size_t)i * N + j];
            mn = fminf(mn, d);
        }
    }
    rv[t] = mn;
    __syncthreads();
    for (int s = 128; s > 0; s >>= 1) {
        if (t < s) rv[t] = fminf(rv[t], rv[t + s]);
        __syncthreads();
    }
    if (t == 0) {
        float dp = fminf(rv[0], dmax[b]);
        double p = (double)dp * (double)__uint_as_float(bi);
        float sf = (float)p;
        uint32_t sb = (sf < 0x1p-126f) ? 0u : __float_as_uint(sf);
        keys[b * N + i] = ((unsigned long long)sb << 32)
                        | (unsigned long long)(0xFFFFFFFFu - (uint32_t)i);
    }
}

// ---------------------------------------------------------------------------
// K4: per-batch bitonic sort of packed keys, descending -> top M indices.
__global__ __launch_bounds__(1024) void k_topm(const unsigned long long* __restrict__ keys,
                                               int* __restrict__ sidx) {
    constexpr int SZ = 4096;
    int b = blockIdx.x, t = threadIdx.x;
    __shared__ unsigned long long ks[SZ];
    for (int i = t; i < SZ; i += 1024) ks[i] = (i < N) ? keys[b * N + i] : 0ull;
    __syncthreads();
    for (int k = 2; k <= SZ; k <<= 1) {
        for (int j = k >> 1; j > 0; j >>= 1) {
            for (int i = t; i < SZ; i += 1024) {
                int ixj = i ^ j;
                if (ixj > i) {
                    bool up = ((i & k) == 0);
                    unsigned long long a = ks[i], c2 = ks[ixj];
                    bool doSwap = up ? (a < c2) : (a > c2);  // descending
                    if (doSwap) { ks[i] = c2; ks[ixj] = a; }
                }
            }
            __syncthreads();
        }
    }
    for (int m = t; m < M; m += 1024)
        sidx[b * M + m] = (int)(0xFFFFFFFFu - (uint32_t)(ks[m] & 0xFFFFFFFFull));
}

// ---------------------------------------------------------------------------
// K5 v2: gather centers TRANSPOSED: cenT[b][c][m] = y[b][c][sidx[m]].
__global__ __launch_bounds__(256) void k_cen(const float* __restrict__ y,
                                             const int* __restrict__ sidx,
                                             const float* __restrict__ ynorm,
                                             float* __restrict__ cenT,
                                             float* __restrict__ cnorm) {
    const int b = blockIdx.y;
    const int m = blockIdx.x * 256 + threadIdx.x;
    if (m >= M) return;
    const int j = sidx[b * M + m];
    cnorm[b * M + m] = ynorm[b * N + j];
    const float* yb = y + (size_t)b * C * N;
    float* ct = cenT + (size_t)b * C * M;
    #pragma unroll 8
    for (int c = 0; c < C; ++c)
        ct[(size_t)c * M + m] = yb[(size_t)c * N + j];
}

// ---------------------------------------------------------------------------
// K6 v3 (xT path, validated round 11)
__global__ __launch_bounds__(256) void k_assign_t(const float* __restrict__ xT,
                                                  const float* __restrict__ cenT,
                                                  const float* __restrict__ xnorm,
                                                  const float* __restrict__ cnorm,
                                                  float* __restrict__ assign,
                                                  int* __restrict__ nnidx) {
    const int b  = blockIdx.y;
    const int i0 = blockIdx.x * 8;
    const int t  = threadIdx.x;

    __shared__ __align__(16) float Ss[8][788];
    __shared__ float xnS[8];

    const float* xTb = xT + (size_t)b * N * C;
    const float* ct  = cenT + (size_t)b * C * M;

    if (t < 8) xnS[t] = xnorm[b * N + i0 + t];
    __syncthreads();

    if (t < 196) {
        const int mt = 4 * t;
        float acc[8][4];
        #pragma unroll
        for (int r = 0; r < 8; ++r)
            #pragma unroll
            for (int q = 0; q < 4; ++q) acc[r][q] = 0.f;

        for (int c0 = 0; c0 < C; c0 += 4) {
            float4 bq0 = *reinterpret_cast<const float4*>(ct + (size_t)(c0 + 0) * M + mt);
            float4 bq1 = *reinterpret_cast<const float4*>(ct + (size_t)(c0 + 1) * M + mt);
            float4 bq2 = *reinterpret_cast<const float4*>(ct + (size_t)(c0 + 2) * M + mt);
            float4 bq3 = *reinterpret_cast<const float4*>(ct + (size_t)(c0 + 3) * M + mt);
            #pragma unroll
            for (int r = 0; r < 8; ++r) {
                float4 a4 = *reinterpret_cast<const float4*>(
                    xTb + (size_t)(i0 + r) * C + c0);   // wave-uniform addr
                acc[r][0] += a4.x * bq0.x; acc[r][1] += a4.x * bq0.y;
                acc[r][2] += a4.x * bq0.z; acc[r][3] += a4.x * bq0.w;
                acc[r][0] += a4.y * bq1.x; acc[r][1] += a4.y * bq1.y;
                acc[r][2] += a4.y * bq1.z; acc[r][3] += a4.y * bq1.w;
                acc[r][0] += a4.z * bq2.x; acc[r][1] += a4.z * bq2.y;
                acc[r][2] += a4.z * bq2.z; acc[r][3] += a4.z * bq2.w;
                acc[r][0] += a4.w * bq3.x; acc[r][1] += a4.w * bq3.y;
                acc[r][2] += a4.w * bq3.z; acc[r][3] += a4.w * bq3.w;
            }
        }

        float4 cn4 = *reinterpret_cast<const float4*>(cnorm + (size_t)b * M + mt);
        float cn[4] = {cn4.x, cn4.y, cn4.z, cn4.w};
        #pragma unroll
        for (int r = 0; r < 8; ++r) {
            float xn = xnS[r];
            float sv[4];
            #pragma unroll
            for (int q = 0; q < 4; ++q)
                sv[q] = -(xn + cn[q] - 2.f * acc[r][q]);
            *reinterpret_cast<float4*>(&Ss[r][mt]) =
                make_float4(sv[0], sv[1], sv[2], sv[3]);
        }
    }
    __syncthreads();

    const int r = t >> 5;
    const int l = t & 31;

    float lm = -FLT_MAX;
    for (int m = l; m < M; m += 32) lm = fmaxf(lm, Ss[r][m]);
    #pragma unroll
    for (int off = 16; off > 0; off >>= 1)
        lm = fmaxf(lm, __shfl_xor(lm, off, 32));
    const float smax = lm;

    float ls = 0.f;
    for (int m = l; m < M; m += 32) ls += expf(Ss[r][m] - smax);
    #pragma unroll
    for (int off = 16; off > 0; off >>= 1)
        ls += __shfl_xor(ls, off, 32);
    const float inv = 1.f / ls;

    float* arow = assign + ((size_t)b * N + i0 + r) * M;
    for (int m = l; m < M; m += 32) arow[m] = expf(Ss[r][m] - smax) * inv;

    for (int round = 0; round < TK; ++round) {
        float lv = -FLT_MAX; int li = M;
        for (int m = l; m < M; m += 32) {
            float v = Ss[r][m];
            if (v > lv) { lv = v; li = m; }
        }
        #pragma unroll
        for (int off = 16; off > 0; off >>= 1) {
            float ov = __shfl_xor(lv, off, 32);
            int   oi = __shfl_xor(li, off, 32);
            if (ov > lv || (ov == lv && oi < li)) { lv = ov; li = oi; }
        }
        if (l == 0) {
            nnidx[((size_t)b * N + i0 + r) * TK + round] = li;
            Ss[r][li] = -FLT_MAX;
        }
        __syncthreads();
    }
}

// ---------------------------------------------------------------------------
// K6 v2 (fallback, validated round 8)
__global__ __launch_bounds__(256) void k_assign(const float* __restrict__ x,
                                                const float* __restrict__ cenT,
                                                const float* __restrict__ xnorm,
                                                const float* __restrict__ cnorm,
                                                float* __restrict__ assign,
                                                int* __restrict__ nnidx) {
    const int b  = blockIdx.y;
    const int i0 = blockIdx.x * 8;
    const int t  = threadIdx.x;

    __shared__ __align__(16) float xiS[8][100];
    __shared__ __align__(16) float Ss[8][788];
    __shared__ float xnS[8];

    const float* xb = x + (size_t)b * C * N;
    const float* ct = cenT + (size_t)b * C * M;

    for (int e = t; e < C * 2; e += 256) {
        int c = e >> 1, n4 = (e & 1) << 2;
        float4 v = *reinterpret_cast<const float4*>(xb + (size_t)c * N + i0 + n4);
        xiS[n4 + 0][c] = v.x;
        xiS[n4 + 1][c] = v.y;
        xiS[n4 + 2][c] = v.z;
        xiS[n4 + 3][c] = v.w;
    }
    if (t < 8) xnS[t] = xnorm[b * N + i0 + t];
    __syncthreads();

    if (t < 196) {
        const int mt = 4 * t;
        float acc[8][4];
        #pragma unroll
        for (int r = 0; r < 8; ++r)
            #pragma unroll
            for (int q = 0; q < 4; ++q) acc[r][q] = 0.f;

        for (int c0 = 0; c0 < C; c0 += 4) {
            float4 bq0 = *reinterpret_cast<const float4*>(ct + (size_t)(c0 + 0) * M + mt);
            float4 bq1 = *reinterpret_cast<const float4*>(ct + (size_t)(c0 + 1) * M + mt);
            float4 bq2 = *reinterpret_cast<const float4*>(ct + (size_t)(c0 + 2) * M + mt);
            float4 bq3 = *reinterpret_cast<const float4*>(ct + (size_t)(c0 + 3) * M + mt);
            #pragma unroll
            for (int r = 0; r < 8; ++r) {
                float4 a4 = *reinterpret_cast<const float4*>(&xiS[r][c0]);
                acc[r][0] += a4.x * bq0.x; acc[r][1] += a4.x * bq0.y;
                acc[r][2] += a4.x * bq0.z; acc[r][3] += a4.x * bq0.w;
                acc[r][0] += a4.y * bq1.x; acc[r][1] += a4.y * bq1.y;
                acc[r][2] += a4.y * bq1.z; acc[r][3] += a4.y * bq1.w;
                acc[r][0] += a4.z * bq2.x; acc[r][1] += a4.z * bq2.y;
                acc[r][2] += a4.z * bq2.z; acc[r][3] += a4.z * bq2.w;
                acc[r][0] += a4.w * bq3.x; acc[r][1] += a4.w * bq3.y;
                acc[r][2] += a4.w * bq3.z; acc[r][3] += a4.w * bq3.w;
            }
        }

        float4 cn4 = *reinterpret_cast<const float4*>(cnorm + (size_t)b * M + mt);
        float cn[4] = {cn4.x, cn4.y, cn4.z, cn4.w};
        #pragma unroll
        for (int r = 0; r < 8; ++r) {
            float xn = xnS[r];
            float sv[4];
            #pragma unroll
            for (int q = 0; q < 4; ++q)
                sv[q] = -(xn + cn[q] - 2.f * acc[r][q]);
            *reinterpret_cast<float4*>(&Ss[r][mt]) =
                make_float4(sv[0], sv[1], sv[2], sv[3]);
        }
    }
    __syncthreads();

    const int r = t >> 5;
    const int l = t & 31;

    float lm = -FLT_MAX;
    for (int m = l; m < M; m += 32) lm = fmaxf(lm, Ss[r][m]);
    #pragma unroll
    for (int off = 16; off > 0; off >>= 1)
        lm = fmaxf(lm, __shfl_xor(lm, off, 32));
    const float smax = lm;

    float ls = 0.f;
    for (int m = l; m < M; m += 32) ls += expf(Ss[r][m] - smax);
    #pragma unroll
    for (int off = 16; off > 0; off >>= 1)
        ls += __shfl_xor(ls, off, 32);
    const float inv = 1.f / ls;

    float* arow = assign + ((size_t)b * N + i0 + r) * M;
    for (int m = l; m < M; m += 32) arow[m] = expf(Ss[r][m] - smax) * inv;

    for (int round = 0; round < TK; ++round) {
        float lv = -FLT_MAX; int li = M;
        for (int m = l; m < M; m += 32) {
            float v = Ss[r][m];
            if (v > lv) { lv = v; li = m; }
        }
        #pragma unroll
        for (int off = 16; off > 0; off >>= 1) {
            float ov = __shfl_xor(lv, off, 32);
            int   oi = __shfl_xor(li, off, 32);
            if (ov > lv || (ov == lv && oi < li)) { lv = ov; li = oi; }
        }
        if (l == 0) {
            nnidx[((size_t)b * N + i0 + r) * TK + round] = li;
            Ss[r][li] = -FLT_MAX;
        }
        __syncthreads();
    }
}

// ---------------------------------------------------------------------------
// K7a: partial agg over an n-slice: aggpart[b][s][m][c] = sum_{n in slice}
// assign[n][m]*x[c][n]; masspart[b][s][m] = sum assign[n][m].
// Inner structure identical to the validated k_agg; no mass division here.
__global__ __launch_bounds__(256) void k_agg_part(const float* __restrict__ assign,
                                                  const float* __restrict__ x,
                                                  float* __restrict__ aggpart,
                                                  float* __restrict__ masspart) {
    const int b = blockIdx.z;
    const int s = blockIdx.y;
    const int m0 = blockIdx.x * 16;
    const int t = threadIdx.x;
    __shared__ float As[64][16];
    __shared__ float Xs[96][65];

    float acc[6] = {0.f, 0.f, 0.f, 0.f, 0.f, 0.f};
    float massacc = 0.f;

    const int nbeg = s * (N / NSPLIT);
    const int nend = nbeg + (N / NSPLIT);

    for (int n0 = nbeg; n0 < nend; n0 += 64) {
        for (int e = t; e < 64 * 16; e += 256) {
            int nn = e >> 4, mm = e & 15;
            As[nn][mm] = assign[((size_t)b * N + n0 + nn) * M + m0 + mm];
        }
        for (int e = t; e < 96 * 64; e += 256) {
            int c = e >> 6, nn = e & 63;
            Xs[c][nn] = x[((size_t)b * C + c) * N + n0 + nn];
        }
        __syncthreads();
        if (t < 16) {
            #pragma unroll
            for (int nn = 0; nn < 64; ++nn) massacc += As[nn][t];
        }
        #pragma unroll
        for (int u = 0; u < 6; ++u) {
            int e = t + u * 256;
            int mm = e & 15, c = e >> 4;
            float a = acc[u];
            #pragma unroll 8
            for (int nn = 0; nn < 64; ++nn) a += As[nn][mm] * Xs[c][nn];
            acc[u] = a;
        }
        __syncthreads();
    }
    if (t < 16) masspart[((size_t)b * NSPLIT + s) * M + m0 + t] = massacc;
    float* ap = aggpart + (((size_t)b * NSPLIT + s) * M) * C;
    #pragma unroll
    for (int u = 0; u < 6; ++u) {
        int e = t + u * 256;
        int mm = e & 15, c = e >> 4;
        ap[(size_t)(m0 + mm) * C + c] = acc[u];
    }
}

// ---------------------------------------------------------------------------
// K7b: reduce the NSPLIT partials (fixed s order), divide by mass+1e-6.
__global__ __launch_bounds__(256) void k_aggred(const float* __restrict__ aggpart,
                                                const float* __restrict__ masspart,
                                                float* __restrict__ aggws) {
    const int b = blockIdx.y;
    const int e = blockIdx.x * 256 + threadIdx.x;   // e = m*C + c
    if (e >= M * C) return;
    const int m = e / C;
    float a = 0.f, ms = 0.f;
    #pragma unroll
    for (int s = 0; s < NSPLIT; ++s) {
        a  += aggpart[(((size_t)b * NSPLIT + s) * M) * C + e];
        ms += masspart[((size_t)b * NSPLIT + s) * M + m];
    }
    aggws[(size_t)b * M * C + e] = a / (ms + 1e-6f);
}

// ---------------------------------------------------------------------------
// K8: per-center FFN with residual; writes updated agg (ws) and `refined`
__global__ __launch_bounds__(128) void k_ffn(const float* __restrict__ w1,
                                             const float* __restrict__ b1,
                                             const float* __restrict__ g1,
                                             const float* __restrict__ bt1,
                                             const float* __restrict__ w2,
                                             const float* __restrict__ b2,
                                             const float* __restrict__ g2,
                                             const float* __restrict__ bt2,
                                             float* __restrict__ aggws,
                                             float* __restrict__ refined) {
    const int m = blockIdx.x;
    const int b = blockIdx.y;
    const int t = threadIdx.x;
    __shared__ float ar[C];
    __shared__ float hd[C4];

    if (t < C) ar[t] = aggws[((size_t)b * M + m) * C + t];
    __syncthreads();

    for (int o = t; o < C4; o += 128) {
        const float* w = w1 + (size_t)o * C;
        float h = b1[o];
        #pragma unroll 8
        for (int c = 0; c < C; ++c) h += w[c] * ar[c];
        h = h * g1[o] + bt1[o];
        hd[o] = fmaxf(h, 0.f);
    }
    __syncthreads();

    if (t < C) {
        const float* w = w2 + (size_t)t * C4;
        float f = b2[t];
        #pragma unroll 8
        for (int o = 0; o < C4; ++o) f += w[o] * hd[o];
        float v = ar[t] + (f * g2[t] + bt2[t]);
        aggws[((size_t)b * M + m) * C + t] = v;
        refined[((size_t)b * C + t) * M + m] = v;
    }
}

// ---------------------------------------------------------------------------
// K9: rel = max over top-5 agg rows - xf; interleaved xcat;
// out = relu((nn_w @ xcat + nn_b) * g + bt), stored (B, OUT, N)
__global__ __launch_bounds__(256) void k_final(const float* __restrict__ x,
                                               const float* __restrict__ aggws,
                                               const int* __restrict__ nnidx,
                                               const float* __restrict__ nnw,
                                               const float* __restrict__ nnb,
                                               const float* __restrict__ nng,
                                               const float* __restrict__ nnbt,
                                               float* __restrict__ out) {
    const int b = blockIdx.y;
    const int n0 = blockIdx.x * 16;
    const int t = threadIdx.x;
    __shared__ float xc[16][193];
    __shared__ int nid[16 * TK];

    if (t < 16 * TK) nid[t] = nnidx[((size_t)b * N + n0) * TK + t];
    __syncthreads();

    for (int e = t; e < C * 16; e += 256) {
        int c = e >> 4, r = e & 15;
        float xv = x[((size_t)b * C + c) * N + n0 + r];
        float mx = -FLT_MAX;
        #pragma unroll
        for (int k = 0; k < TK; ++k) {
            int j = nid[r * TK + k];
            mx = fmaxf(mx, aggws[((size_t)b * M + j) * C + c]);
        }
        xc[r][2 * c]     = xv;
        xc[r][2 * c + 1] = mx - xv;
    }
    __syncthreads();

    const int r = t & 15;
    const int og = t >> 4;
    #pragma unroll
    for (int oo = 0; oo < 12; ++oo) {
        int o = og + (oo << 4);
        const float* w = nnw + (size_t)o * (2 * C);
        float a = nnb[o];
        #pragma unroll 8
        for (int cc = 0; cc < 2 * C; ++cc) a += w[cc] * xc[r][cc];
        a = a * nng[o] + nnbt[o];
        out[((size_t)b * OUT + o) * N + n0 + r] = fmaxf(a, 0.f);
    }
}

// ---------------------------------------------------------------------------
extern "C" void kernel_launch(void* const* d_in, const int* in_sizes, int n_in,
                              void* d_out, int out_size, void* d_ws, size_t ws_size,
                              hipStream_t stream) {
    const float* x    = (const float*)d_in[0];
    const float* rel  = (const float*)d_in[1];
    const float* y    = (const float*)d_in[2];
    const float* w1   = (const float*)d_in[3];
    const float* b1   = (const float*)d_in[4];
    const float* g1   = (const float*)d_in[5];
    const float* bt1  = (const float*)d_in[6];
    const float* w2   = (const float*)d_in[7];
    const float* b2   = (const float*)d_in[8];
    const float* g2   = (const float*)d_in[9];
    const float* bt2  = (const float*)d_in[10];
    const float* nnw  = (const float*)d_in[11];
    const float* nnb  = (const float*)d_in[12];
    const float* nng  = (const float*)d_in[13];
    const float* nnbt = (const float*)d_in[14];

    float* out     = (float*)d_out;
    float* refined = out + (size_t)B * OUT * N;

    char* w = (char*)d_ws;
    auto alloc = [&](size_t nbytes) -> void* {
        void* p = (void*)w;
        w += (nbytes + 255) & ~(size_t)255;
        return p;
    };
    float*    ynorm    = (float*)   alloc((size_t)B * N * 4);
    float*    xnorm    = (float*)   alloc((size_t)B * N * 4);
    uint32_t* densbits = (uint32_t*)alloc((size_t)B * N * 4);
    float*    rowmax   = (float*)   alloc((size_t)B * N * 4);
    float*    dmaxv    = (float*)   alloc((size_t)B * 4);
    unsigned long long* keys = (unsigned long long*)alloc((size_t)B * N * 8);
    int*      sidx     = (int*)     alloc((size_t)B * M * 4);
    float*    cnorm    = (float*)   alloc((size_t)B * M * 4);
    float*    cenT     = (float*)   alloc((size_t)B * C * M * 4);
    float*    aggws    = (float*)   alloc((size_t)B * M * C * 4);
    int*      nnidx    = (int*)     alloc((size_t)B * N * TK * 4);
    float*    assign   = (float*)   alloc((size_t)B * N * M * 4);
    float*    aggpart  = (float*)   alloc((size_t)B * NSPLIT * M * C * 4);
    float*    masspart = (float*)   alloc((size_t)B * NSPLIT * M * 4);

    // optional transposed copies (gated on workspace size)
    size_t used = (size_t)(w - (char*)d_ws);
    size_t tbytes = (size_t)B * N * C * 4;
    float* yT = nullptr;
    float* xT = nullptr;
    if (ws_size >= used + 2 * (tbytes + 256)) {
        yT = (float*)alloc(tbytes);
        xT = (float*)alloc(tbytes);
    }

    if (yT) k_tr<<<dim3(N / 32, C / 32, B), dim3(256), 0, stream>>>(y, x, yT, xT);

    k_norms<<<dim3((B * N + 255) / 256), dim3(256), 0, stream>>>(y, x, ynorm, xnorm);

    if (yT)
        k_density_t<<<dim3(N / DR, B), dim3(256), 0, stream>>>(y, yT, rel, ynorm, densbits, rowmax);
    else
        k_density<<<dim3(N / DR, B), dim3(256), 0, stream>>>(y, rel, ynorm, densbits, rowmax);

    k_dmax<<<dim3(B), dim3(256), 0, stream>>>(rowmax, dmaxv);
    k_score<<<dim3(N, B), dim3(256), 0, stream>>>(y, rel, ynorm, densbits, dmaxv, keys);
    k_topm<<<dim3(B), dim3(1024), 0, stream>>>(keys, sidx);
    k_cen<<<dim3((M + 255) / 256, B), dim3(256), 0, stream>>>(y, sidx, ynorm, cenT, cnorm);

    if (xT)
        k_assign_t<<<dim3(N / 8, B), dim3(256), 0, stream>>>(xT, cenT, xnorm, cnorm, assign, nnidx);
    else
        k_assign<<<dim3(N / 8, B), dim3(256), 0, stream>>>(x, cenT, xnorm, cnorm, assign, nnidx);

    k_agg_part<<<dim3(M / 16, NSPLIT, B), dim3(256), 0, stream>>>(assign, x, aggpart, masspart);
    k_aggred<<<dim3((M * C + 255) / 256, B), dim3(256), 0, stream>>>(aggpart, masspart, aggws);
    k_ffn<<<dim3(M, B), dim3(128), 0, stream>>>(w1, b1, g1, bt1, w2, b2, g2, bt2, aggws, refined);
    k_final<<<dim3(N / 16, B), dim3(256), 0, stream>>>(x, aggws, nnidx, nnw, nnb, nng, nnbt, out);
}